// Round 6
// baseline (235.960 us; speedup 1.0000x reference)
//
#include <hip/hip_runtime.h>
#include <hip/hip_bf16.h>

typedef __bf16 bf16x8 __attribute__((ext_vector_type(8)));
typedef __bf16 bf16x4 __attribute__((ext_vector_type(4)));
typedef float  f32x4  __attribute__((ext_vector_type(4)));

#define GLOBAL_AS __attribute__((address_space(1)))
#define LDS_AS    __attribute__((address_space(3)))

__device__ __forceinline__ void glds16(const void* g, void* l) {
  __builtin_amdgcn_global_load_lds((const GLOBAL_AS void*)g, (LDS_AS void*)l, 16, 0, 0);
}

// ---------------- prep: f32->bf16 converts (x, W_qkv, W_out) + RoPE cos/sin table ----------------
__global__ __launch_bounds__(256) void prep_kernel(
    const float* __restrict__ a, __bf16* __restrict__ da, int na4,
    const float* __restrict__ b, __bf16* __restrict__ db, int nb4,
    const float* __restrict__ c, __bf16* __restrict__ dc, int nc4,
    float2* __restrict__ tab) {
  int i = blockIdx.x * 256 + threadIdx.x;
  const float* s; __bf16* d; int j = i;
  if (i < na4) { s = a; d = da; }
  else if ((j = i - na4) < nb4) { s = b; d = db; }
  else if ((j = i - na4 - nb4) < nc4) { s = c; d = dc; }
  else {
    j = i - na4 - nb4 - nc4;
    if (j < 65536) {                     // [l(2048)][j(32)] cos/sin
      int l = j >> 5, jj = j & 31;
      float inv = 1.0f / powf(10000.0f, (float)jj * (1.0f / 32.0f));
      float ang = (float)l * inv;
      tab[j] = make_float2(cosf(ang), sinf(ang));
    }
    return;
  }
  float4 f = ((const float4*)s)[j];
  bf16x4 o;
  o[0] = (__bf16)f.x; o[1] = (__bf16)f.y; o[2] = (__bf16)f.z; o[3] = (__bf16)f.w;
  ((bf16x4*)d)[j] = o;
}

// ---------------- GEMM C = A * B^T (+bias), A[M,K] bf16, B[N,K] bf16 ----------------
// 128x128 tile, BK=32, 4 waves (2x2), 16x16x32 bf16 MFMA. 1-D grid + XCD swizzle.
// EPI 0: fused RMSNorm+RoPE -> q/k [b,h,l,d] bf16; v TRANSPOSED [b,h,d,l] bf16.
// EPI 1: d_out f32.
template <int EPI>
__global__ __launch_bounds__(256) void gemm_bt(
    const __bf16* __restrict__ A, const __bf16* __restrict__ Bm, int K, int nbn,
    const float* __restrict__ bias,
    __bf16* __restrict__ qo, __bf16* __restrict__ ko, __bf16* __restrict__ vo,
    float* __restrict__ out,
    const float* __restrict__ qg, const float* __restrict__ kg,
    const float2* __restrict__ tab) {
  __shared__ __bf16 As[128 * 32];
  __shared__ __bf16 Bs[128 * 32];
  const int t = threadIdx.x;
  const int nwg = gridDim.x;
  const int id = blockIdx.x;
  const int swz = (id & 7) * (nwg >> 3) + (id >> 3);
  const int bn = swz % nbn, bm = swz / nbn;
  const int lane = t & 63, w = t >> 6;
  const int wr = w >> 1, wc = w & 1;
  const int lr = lane & 15, lg = lane >> 4;
  const size_t rowA0 = (size_t)bm * 128, rowB0 = (size_t)bn * 128;

  f32x4 acc[4][4] = {};

  for (int k0 = 0; k0 < K; k0 += 32) {
    __syncthreads();
#pragma unroll
    for (int i = 0; i < 2; ++i) {
      int c = t + i * 256;
      int rr = c >> 2, c8 = (c & 3) * 8;
      glds16(A + (rowA0 + rr) * K + k0 + c8, As + c * 8);
      glds16(Bm + (rowB0 + rr) * K + k0 + c8, Bs + c * 8);
    }
    __syncthreads();
    bf16x8 af[4], bfr[4];
#pragma unroll
    for (int i = 0; i < 4; ++i) {
      af[i]  = *(const bf16x8*)&As[(wr * 64 + i * 16 + lr) * 32 + lg * 8];
      bfr[i] = *(const bf16x8*)&Bs[(wc * 64 + i * 16 + lr) * 32 + lg * 8];
    }
#pragma unroll
    for (int mi = 0; mi < 4; ++mi)
#pragma unroll
      for (int ni = 0; ni < 4; ++ni)
        acc[mi][ni] = __builtin_amdgcn_mfma_f32_16x16x32_bf16(af[mi], bfr[ni], acc[mi][ni], 0, 0, 0);
  }

  // epilogue: C/D layout col=lane&15, row=(lane>>4)*4+reg (m89-verified)
  if constexpr (EPI == 0) {
    const int sect = bn >> 3;                // 0:q 1:k 2:v
    const int h = (bn * 2 + wc) & 15;
    float bbv[4];
#pragma unroll
    for (int ni = 0; ni < 4; ++ni) bbv[ni] = bias[bn * 128 + wc * 64 + ni * 16 + lr];
    if (sect < 2) {
      __bf16* dst = sect ? ko : qo;
      const float* g = sect ? kg : qg;
      float gam[4];
#pragma unroll
      for (int ni = 0; ni < 4; ++ni) gam[ni] = g[ni * 16 + lr];   // d = ni*16+lr
      // phase 1: bias add + per-row sum-of-squares (all 16 rows)
      float ss[4][4];
#pragma unroll
      for (int mi = 0; mi < 4; ++mi)
#pragma unroll
        for (int r = 0; r < 4; ++r) {
          float s = 0.0f;
#pragma unroll
          for (int ni = 0; ni < 4; ++ni) {
            acc[mi][ni][r] += bbv[ni];
            s += acc[mi][ni][r] * acc[mi][ni][r];
          }
          ss[mi][r] = s;
        }
      // phase 2: batched shfl reduction (16-way ILP per round)
#pragma unroll
      for (int step = 1; step <= 8; step <<= 1)
#pragma unroll
        for (int mi = 0; mi < 4; ++mi)
#pragma unroll
          for (int r = 0; r < 4; ++r)
            ss[mi][r] += __shfl_xor(ss[mi][r], step);
      // phase 3: normalize + RoPE + store
#pragma unroll
      for (int mi = 0; mi < 4; ++mi) {
#pragma unroll
        for (int r = 0; r < 4; ++r) {
          int m = bm * 128 + wr * 64 + mi * 16 + lg * 4 + r;
          int b_ = m >> 11, l = m & 2047;
          float rinv = rsqrtf(ss[mi][r] * (1.0f / 64.0f) + 1e-6f);
          float v0 = acc[mi][0][r] * rinv * gam[0];
          float v1 = acc[mi][1][r] * rinv * gam[1];
          float v2 = acc[mi][2][r] * rinv * gam[2];
          float v3 = acc[mi][3][r] * rinv * gam[3];
          float2 cs0 = tab[l * 32 + lr];
          float2 cs1 = tab[l * 32 + 16 + lr];
          float o0 = v0 * cs0.x - v2 * cs0.y;
          float o2 = v2 * cs0.x + v0 * cs0.y;
          float o1 = v1 * cs1.x - v3 * cs1.y;
          float o3 = v3 * cs1.x + v1 * cs1.y;
          size_t base = ((size_t)(b_ * 16 + h) * 2048 + l) * 64;
          dst[base + lr]      = (__bf16)o0;
          dst[base + 16 + lr] = (__bf16)o1;
          dst[base + 32 + lr] = (__bf16)o2;
          dst[base + 48 + lr] = (__bf16)o3;
        }
      }
    } else {
      // V^T [b,h,d,l]
#pragma unroll
      for (int mi = 0; mi < 4; ++mi) {
#pragma unroll
        for (int ni = 0; ni < 4; ++ni) {
          int d = ni * 16 + lr;
#pragma unroll
          for (int r = 0; r < 4; ++r) {
            int m = bm * 128 + wr * 64 + mi * 16 + lg * 4 + r;
            int b_ = m >> 11, l = m & 2047;
            vo[((size_t)((b_ * 16 + h) * 64 + d)) * 2048 + l] = (__bf16)(acc[mi][ni][r] + bbv[ni]);
          }
        }
      }
    }
  } else {
#pragma unroll
    for (int mi = 0; mi < 4; ++mi) {
      int m0 = bm * 128 + wr * 64 + mi * 16 + lg * 4;
#pragma unroll
      for (int ni = 0; ni < 4; ++ni) {
        int n = bn * 128 + wc * 64 + ni * 16 + lr;
        float bb = bias[n];
#pragma unroll
        for (int r = 0; r < 4; ++r)
          out[(size_t)(m0 + r) * 1024 + n] = acc[mi][ni][r] + bb;
      }
    }
  }
}

// ---------------- flash attention: fully wave-independent, no barriers ----------------
// 2048 blocks x 64 threads. Each wave owns (fq, bh, 32 q-rows). K / V^T fragments loaded
// directly global->VGPR (L2-resident); P round-trips through a private 4KB LDS stripe
// (wave-local, no sync). id->rank pairing balances per-CU work under round-robin dispatch.
__global__ __launch_bounds__(64, 3) void attn_kernel(
    const __bf16* __restrict__ qb, const __bf16* __restrict__ kb,
    const __bf16* __restrict__ vT, __bf16* __restrict__ ob) {
  __shared__ char Ps[4096];              // P [32][64] bf16, XOR-swizzled

  const int id = blockIdx.x;             // 0..2047
  const int rank = (id < 1024) ? id : 3071 - id;
  const int fq = rank >> 7;              // 0..15
  const int bh = (rank >> 2) & 31;
  const int qq = rank & 3;               // q-quarter within the frame
  const int lane = threadIdx.x;
  const int lr = lane & 15, lg = lane >> 4;
  const size_t hoff = (size_t)bh * (2048 * 64);
  const int q0 = fq * 128 + qq * 32;

  // Q B-operand frags from global: lane holds Q[q0+mf*16+lr][kk*32+lg*8 ..+8]
  bf16x8 aq[2][2];
#pragma unroll
  for (int kk = 0; kk < 2; ++kk)
#pragma unroll
    for (int mf = 0; mf < 2; ++mf)
      aq[kk][mf] = *(const bf16x8*)(qb + hoff + (size_t)(q0 + mf * 16 + lr) * 64 + kk * 32 + lg * 8);

  f32x4 acc[2][4] = {};                  // O^T accumulator
  float m_run[2] = {-INFINITY, -INFINITY};
  float l_run[2] = {0.0f, 0.0f};

  const int fkS = (fq == 15) ? 2 : 0;    // frame 0 excluded for the last frame
  const int fkE = (fq + 1) * 2;          // exclusive, 64-row k-tiles

  for (int fk = fkS; fk < fkE; ++fk) {
    // K A-operand frags straight from global
    const __bf16* kbase = kb + hoff + (size_t)(fk * 64) * 64;
    bf16x8 kf[2][4];
#pragma unroll
    for (int nf = 0; nf < 4; ++nf)
#pragma unroll
      for (int kk = 0; kk < 2; ++kk)
        kf[kk][nf] = *(const bf16x8*)(kbase + (nf * 16 + lr) * 64 + kk * 32 + lg * 8);

    // S^T = K Q^T
    f32x4 st[2][4] = {};
    __builtin_amdgcn_s_setprio(1);
#pragma unroll
    for (int kk = 0; kk < 2; ++kk)
#pragma unroll
      for (int nf = 0; nf < 4; ++nf) {
        st[0][nf] = __builtin_amdgcn_mfma_f32_16x16x32_bf16(kf[kk][nf], aq[kk][0], st[0][nf], 0, 0, 0);
        st[1][nf] = __builtin_amdgcn_mfma_f32_16x16x32_bf16(kf[kk][nf], aq[kk][1], st[1][nf], 0, 0, 0);
      }
    __builtin_amdgcn_s_setprio(0);

    // V^T A-operand frags issued now; latency hides under softmax
    const __bf16* vbase = vT + hoff + fk * 64;
    bf16x8 vf[2][4];
#pragma unroll
    for (int df = 0; df < 4; ++df)
#pragma unroll
      for (int kk = 0; kk < 2; ++kk)
        vf[kk][df] = *(const bf16x8*)(vbase + (size_t)(df * 16 + lr) * 2048 + kk * 32 + lg * 8);

    // in-register online softmax (lane owns q=lr per mf; k over (nf,r) in-lane + lg cross-lane)
#pragma unroll
    for (int mf = 0; mf < 2; ++mf) {
      float mx = st[mf][0][0];
#pragma unroll
      for (int nf = 0; nf < 4; ++nf)
#pragma unroll
        for (int r = 0; r < 4; ++r) mx = fmaxf(mx, st[mf][nf][r]);
      mx *= 0.125f;
      mx = fmaxf(mx, __shfl_xor(mx, 16));
      mx = fmaxf(mx, __shfl_xor(mx, 32));
      float mnew = m_run[mf], cr = 1.0f;
      if (__any(mx > m_run[mf] + 8.0f)) {       // T13 defer-max
        mnew = fmaxf(m_run[mf], mx);
        cr = __expf(m_run[mf] - mnew);
#pragma unroll
        for (int df = 0; df < 4; ++df) acc[mf][df] *= cr;
      }
      float lsum = 0.0f;
#pragma unroll
      for (int nf = 0; nf < 4; ++nf)
#pragma unroll
        for (int r = 0; r < 4; ++r) {
          float p = __expf(fmaf(st[mf][nf][r], 0.125f, -mnew));
          st[mf][nf][r] = p;
          lsum += p;
        }
      lsum += __shfl_xor(lsum, 16);
      lsum += __shfl_xor(lsum, 32);
      l_run[mf] = l_run[mf] * cr + lsum;
      m_run[mf] = mnew;

      // P^T -> LDS as P[q][k] (wave-local, no sync): 4 consecutive k per write
#pragma unroll
      for (int nf = 0; nf < 4; ++nf) {
        int row = mf * 16 + lr;
        bf16x4 pw;
#pragma unroll
        for (int r = 0; r < 4; ++r) pw[r] = (__bf16)st[mf][nf][r];
        int slot = nf * 2 + (lg >> 1);
        *(bf16x4*)(Ps + row * 128 + (((slot ^ (lr & 7)) << 4) | ((lg & 1) * 8))) = pw;
      }
    }

    // O^T += V^T P^T
    __builtin_amdgcn_s_setprio(1);
#pragma unroll
    for (int kk = 0; kk < 2; ++kk) {
      bf16x8 ap[2];
#pragma unroll
      for (int mf = 0; mf < 2; ++mf) {
        int row = mf * 16 + lr;
        ap[mf] = *(const bf16x8*)(Ps + row * 128 + (((kk * 4 + lg) ^ (lr & 7)) << 4));
      }
#pragma unroll
      for (int df = 0; df < 4; ++df) {
        acc[0][df] = __builtin_amdgcn_mfma_f32_16x16x32_bf16(vf[kk][df], ap[0], acc[0][df], 0, 0, 0);
        acc[1][df] = __builtin_amdgcn_mfma_f32_16x16x32_bf16(vf[kk][df], ap[1], acc[1][df], 0, 0, 0);
      }
    }
    __builtin_amdgcn_s_setprio(0);
  }

  // epilogue: O^T -> O; lane has q=lr(+16mf), d=df*16+lg*4+r (consecutive r)
  const int b = bh >> 4, h = bh & 15;
#pragma unroll
  for (int mf = 0; mf < 2; ++mf) {
    float rl = 1.0f / l_run[mf];
    int l = q0 + mf * 16 + lr;
#pragma unroll
    for (int df = 0; df < 4; ++df) {
      bf16x4 ov;
#pragma unroll
      for (int r = 0; r < 4; ++r) ov[r] = (__bf16)(acc[mf][df][r] * rl);
      int d0 = df * 16 + lg * 4;
      *(bf16x4*)(ob + ((size_t)(b * 2048 + l)) * 1024 + h * 64 + d0) = ov;
    }
  }
}

// ---------------- launch ----------------
extern "C" void kernel_launch(void* const* d_in, const int* in_sizes, int n_in,
                              void* d_out, int out_size, void* d_ws, size_t ws_size,
                              hipStream_t stream) {
  (void)in_sizes; (void)n_in; (void)out_size; (void)ws_size;
  const float* x    = (const float*)d_in[0];
  const float* Wqkv = (const float*)d_in[1];
  const float* bqkv = (const float*)d_in[2];
  const float* Wout = (const float*)d_in[3];
  const float* bout = (const float*)d_in[4];
  const float* qg   = (const float*)d_in[5];
  const float* kg   = (const float*)d_in[6];

  char* ws = (char*)d_ws;
  __bf16* xb   = (__bf16*)(ws);                 // 4096x1024       (8 MB)
  __bf16* wqb  = (__bf16*)(ws + 8388608);       // 3072x1024       (6 MB)
  __bf16* wob  = (__bf16*)(ws + 14680064);      // 1024x1024       (2 MB)
  __bf16* qbuf = (__bf16*)(ws + 16777216);      // [2][16][2048][64]
  __bf16* kbuf = (__bf16*)(ws + 25165824);
  __bf16* vbuf = (__bf16*)(ws + 33554432);      // V^T: [2][16][64][2048]
  __bf16* aob  = (__bf16*)(ws + 41943040);      // [2][2048][1024]
  float2* rtab = (float2*)(ws + 50331648);      // [2048][32] cos/sin

  // 2097152 cvt quads + 65536 rope entries = 2162688 items -> 8448 blocks
  prep_kernel<<<8448, 256, 0, stream>>>(x, xb, 1048576, Wqkv, wqb, 786432,
                                        Wout, wob, 262144, rtab);
  gemm_bt<0><<<768, 256, 0, stream>>>(xb, wqb, 1024, 24, bqkv, qbuf, kbuf, vbuf, nullptr,
                                      qg, kg, rtab);
  attn_kernel<<<2048, 64, 0, stream>>>(qbuf, kbuf, vbuf, aob);
  gemm_bt<1><<<256, 256, 0, stream>>>(aob, wob, 1024, 8, bout, nullptr, nullptr, nullptr,
                                      (float*)d_out, nullptr, nullptr, nullptr);
}

// Round 7
// 214.553 us; speedup vs baseline: 1.0998x; 1.0998x over previous
//
#include <hip/hip_runtime.h>
#include <hip/hip_bf16.h>

typedef __bf16 bf16x8 __attribute__((ext_vector_type(8)));
typedef __bf16 bf16x4 __attribute__((ext_vector_type(4)));
typedef float  f32x4  __attribute__((ext_vector_type(4)));

#define GLOBAL_AS __attribute__((address_space(1)))
#define LDS_AS    __attribute__((address_space(3)))

__device__ __forceinline__ void glds16(const void* g, void* l) {
  __builtin_amdgcn_global_load_lds((const GLOBAL_AS void*)g, (LDS_AS void*)l, 16, 0, 0);
}

// ---------------- prep: f32->bf16 converts (x, W_qkv, W_out) + RoPE cos/sin table ----------------
__global__ __launch_bounds__(256) void prep_kernel(
    const float* __restrict__ a, __bf16* __restrict__ da, int na4,
    const float* __restrict__ b, __bf16* __restrict__ db, int nb4,
    const float* __restrict__ c, __bf16* __restrict__ dc, int nc4,
    float2* __restrict__ tab) {
  int i = blockIdx.x * 256 + threadIdx.x;
  const float* s; __bf16* d; int j = i;
  if (i < na4) { s = a; d = da; }
  else if ((j = i - na4) < nb4) { s = b; d = db; }
  else if ((j = i - na4 - nb4) < nc4) { s = c; d = dc; }
  else {
    j = i - na4 - nb4 - nc4;
    if (j < 65536) {                     // [l(2048)][j(32)] cos/sin
      int l = j >> 5, jj = j & 31;
      float inv = 1.0f / powf(10000.0f, (float)jj * (1.0f / 32.0f));
      float ang = (float)l * inv;
      tab[j] = make_float2(cosf(ang), sinf(ang));
    }
    return;
  }
  float4 f = ((const float4*)s)[j];
  bf16x4 o;
  o[0] = (__bf16)f.x; o[1] = (__bf16)f.y; o[2] = (__bf16)f.z; o[3] = (__bf16)f.w;
  ((bf16x4*)d)[j] = o;
}

// ---------------- GEMM C = A * B^T (+bias), A[M,K] bf16, B[N,K] bf16 ----------------
// 128x128 tile, BK=32, 4 waves (2x2), 16x16x32 bf16 MFMA. 1-D grid + XCD swizzle.
// EPI 0: fused RMSNorm+RoPE -> q/k [b,h,l,d] bf16; v TRANSPOSED [b,h,d,l] bf16.
// EPI 1: d_out f32.
template <int EPI>
__global__ __launch_bounds__(256) void gemm_bt(
    const __bf16* __restrict__ A, const __bf16* __restrict__ Bm, int K, int nbn,
    const float* __restrict__ bias,
    __bf16* __restrict__ qo, __bf16* __restrict__ ko, __bf16* __restrict__ vo,
    float* __restrict__ out,
    const float* __restrict__ qg, const float* __restrict__ kg,
    const float2* __restrict__ tab) {
  __shared__ __bf16 As[128 * 32];
  __shared__ __bf16 Bs[128 * 32];
  const int t = threadIdx.x;
  const int nwg = gridDim.x;
  const int id = blockIdx.x;
  const int swz = (id & 7) * (nwg >> 3) + (id >> 3);
  const int bn = swz % nbn, bm = swz / nbn;
  const int lane = t & 63, w = t >> 6;
  const int wr = w >> 1, wc = w & 1;
  const int lr = lane & 15, lg = lane >> 4;
  const size_t rowA0 = (size_t)bm * 128, rowB0 = (size_t)bn * 128;

  f32x4 acc[4][4] = {};

  for (int k0 = 0; k0 < K; k0 += 32) {
    __syncthreads();
#pragma unroll
    for (int i = 0; i < 2; ++i) {
      int c = t + i * 256;
      int rr = c >> 2, c8 = (c & 3) * 8;
      glds16(A + (rowA0 + rr) * K + k0 + c8, As + c * 8);
      glds16(Bm + (rowB0 + rr) * K + k0 + c8, Bs + c * 8);
    }
    __syncthreads();
    bf16x8 af[4], bfr[4];
#pragma unroll
    for (int i = 0; i < 4; ++i) {
      af[i]  = *(const bf16x8*)&As[(wr * 64 + i * 16 + lr) * 32 + lg * 8];
      bfr[i] = *(const bf16x8*)&Bs[(wc * 64 + i * 16 + lr) * 32 + lg * 8];
    }
#pragma unroll
    for (int mi = 0; mi < 4; ++mi)
#pragma unroll
      for (int ni = 0; ni < 4; ++ni)
        acc[mi][ni] = __builtin_amdgcn_mfma_f32_16x16x32_bf16(af[mi], bfr[ni], acc[mi][ni], 0, 0, 0);
  }

  // epilogue: C/D layout col=lane&15, row=(lane>>4)*4+reg (m89-verified)
  if constexpr (EPI == 0) {
    const int sect = bn >> 3;                // 0:q 1:k 2:v
    const int h = (bn * 2 + wc) & 15;
    float bbv[4];
#pragma unroll
    for (int ni = 0; ni < 4; ++ni) bbv[ni] = bias[bn * 128 + wc * 64 + ni * 16 + lr];
    if (sect < 2) {
      __bf16* dst = sect ? ko : qo;
      const float* g = sect ? kg : qg;
      float gam[4];
#pragma unroll
      for (int ni = 0; ni < 4; ++ni) gam[ni] = g[ni * 16 + lr];   // d = ni*16+lr
      float ss[4][4];
#pragma unroll
      for (int mi = 0; mi < 4; ++mi)
#pragma unroll
        for (int r = 0; r < 4; ++r) {
          float s = 0.0f;
#pragma unroll
          for (int ni = 0; ni < 4; ++ni) {
            acc[mi][ni][r] += bbv[ni];
            s += acc[mi][ni][r] * acc[mi][ni][r];
          }
          ss[mi][r] = s;
        }
#pragma unroll
      for (int step = 1; step <= 8; step <<= 1)
#pragma unroll
        for (int mi = 0; mi < 4; ++mi)
#pragma unroll
          for (int r = 0; r < 4; ++r)
            ss[mi][r] += __shfl_xor(ss[mi][r], step);
#pragma unroll
      for (int mi = 0; mi < 4; ++mi) {
#pragma unroll
        for (int r = 0; r < 4; ++r) {
          int m = bm * 128 + wr * 64 + mi * 16 + lg * 4 + r;
          int b_ = m >> 11, l = m & 2047;
          float rinv = rsqrtf(ss[mi][r] * (1.0f / 64.0f) + 1e-6f);
          float v0 = acc[mi][0][r] * rinv * gam[0];
          float v1 = acc[mi][1][r] * rinv * gam[1];
          float v2 = acc[mi][2][r] * rinv * gam[2];
          float v3 = acc[mi][3][r] * rinv * gam[3];
          float2 cs0 = tab[l * 32 + lr];
          float2 cs1 = tab[l * 32 + 16 + lr];
          float o0 = v0 * cs0.x - v2 * cs0.y;
          float o2 = v2 * cs0.x + v0 * cs0.y;
          float o1 = v1 * cs1.x - v3 * cs1.y;
          float o3 = v3 * cs1.x + v1 * cs1.y;
          size_t base = ((size_t)(b_ * 16 + h) * 2048 + l) * 64;
          dst[base + lr]      = (__bf16)o0;
          dst[base + 16 + lr] = (__bf16)o1;
          dst[base + 32 + lr] = (__bf16)o2;
          dst[base + 48 + lr] = (__bf16)o3;
        }
      }
    } else {
      // V^T [b,h,d,l]
#pragma unroll
      for (int mi = 0; mi < 4; ++mi) {
#pragma unroll
        for (int ni = 0; ni < 4; ++ni) {
          int d = ni * 16 + lr;
#pragma unroll
          for (int r = 0; r < 4; ++r) {
            int m = bm * 128 + wr * 64 + mi * 16 + lg * 4 + r;
            int b_ = m >> 11, l = m & 2047;
            vo[((size_t)((b_ * 16 + h) * 64 + d)) * 2048 + l] = (__bf16)(acc[mi][ni][r] + bbv[ni]);
          }
        }
      }
    }
  } else {
#pragma unroll
    for (int mi = 0; mi < 4; ++mi) {
      int m0 = bm * 128 + wr * 64 + mi * 16 + lg * 4;
#pragma unroll
      for (int ni = 0; ni < 4; ++ni) {
        int n = bn * 128 + wc * 64 + ni * 16 + lr;
        float bb = bias[n];
#pragma unroll
        for (int r = 0; r < 4; ++r)
          out[(size_t)(m0 + r) * 1024 + n] = acc[mi][ni][r] + bb;
      }
    }
  }
}

// ---------------- flash attention: 8 waves = 4 q-quarters x 2 KV-halves ----------------
// grid 512 (fq,bh via balanced pairing), block 512. KV staged in LDS (shared by all 8 waves),
// each KV-half processes niter = ntiles/2 tiles; halves merged via LDS at the end.
// LDS 64K: K [2][64][64] | V^T [2][64][64] | P stripes 8x4K. 2 blocks/CU -> 4 waves/SIMD.
__global__ __launch_bounds__(512, 4) void attn_kernel(
    const __bf16* __restrict__ qb, const __bf16* __restrict__ kb,
    const __bf16* __restrict__ vT, __bf16* __restrict__ ob) {
  __shared__ char smem[65536];
  char* Kl = smem;                       // [half][64][64] bf16
  char* Vl = smem + 16384;               // [half][64][64] bf16 (V^T rows=d)

  const int id = blockIdx.x;             // 0..511
  const int rank = (id < 256) ? id : 767 - id;   // complementary fq pairing per CU
  const int fq = rank >> 5;
  const int bh = rank & 31;
  const int t = threadIdx.x;
  const int lane = t & 63;
  const int w = t >> 6;                  // 0..7
  const int qq = w & 3;
  const int half = w >> 2;
  const int lr = lane & 15, lg = lane >> 4;
  const size_t hoff = (size_t)bh * (2048 * 64);
  const int q0 = fq * 128 + qq * 32;
  char* Pw = smem + 32768 + w * 4096;    // wave-private P [32][64] bf16

  const int fkS = (fq == 15) ? 2 : 0;
  const int niter = (fq + 1) - (fq == 15 ? 1 : 0);   // tiles per half (ntiles always even)
  const int myT0 = fkS + half * niter;               // this wave's first tile

  // Q fragments direct from global (B-operand: lane holds Q[q0+mf*16+lr][kk*32+lg*8..+8])
  bf16x8 aq[2][2];
#pragma unroll
  for (int kk = 0; kk < 2; ++kk)
#pragma unroll
    for (int mf = 0; mf < 2; ++mf)
      aq[kk][mf] = *(const bf16x8*)(qb + hoff + (size_t)(q0 + mf * 16 + lr) * 64 + kk * 32 + lg * 8);

  // stage tile 0 of both halves (pre-swizzled source, linear LDS dest; 4 glds16/thread)
  {
    int c = t, row = c >> 3, sl = c & 7, sp = sl ^ (row & 7);
    glds16(kb + hoff + (size_t)((fkS) * 64 + row) * 64 + sp * 8,         Kl + c * 16);
    glds16(kb + hoff + (size_t)((fkS + niter) * 64 + row) * 64 + sp * 8, Kl + 8192 + c * 16);
    glds16(vT + hoff + (size_t)row * 2048 + (fkS) * 64 + sp * 8,         Vl + c * 16);
    glds16(vT + hoff + (size_t)row * 2048 + (fkS + niter) * 64 + sp * 8, Vl + 8192 + c * 16);
  }
  __syncthreads();

  f32x4 acc[2][4] = {};                  // O^T accumulator [mf(q)][df(d)]
  float m_run[2] = {-INFINITY, -INFINITY};
  float l_run[2] = {0.0f, 0.0f};

  for (int it = 0; it < niter; ++it) {
    // T14: reg-prefetch next tile of both halves
    const bool pref = (it + 1 < niter);
    bf16x8 rK0, rK1, rV0, rV1;
    if (pref) {
      int c = t, row = c >> 3, sl = c & 7, sp = sl ^ (row & 7);
      rK0 = *(const bf16x8*)(kb + hoff + (size_t)((fkS + it + 1) * 64 + row) * 64 + sp * 8);
      rK1 = *(const bf16x8*)(kb + hoff + (size_t)((fkS + niter + it + 1) * 64 + row) * 64 + sp * 8);
      rV0 = *(const bf16x8*)(vT + hoff + (size_t)row * 2048 + (fkS + it + 1) * 64 + sp * 8);
      rV1 = *(const bf16x8*)(vT + hoff + (size_t)row * 2048 + (fkS + niter + it + 1) * 64 + sp * 8);
    }
    char* Kc = Kl + half * 8192;
    char* Vc = Vl + half * 8192;

    // S^T = K Q^T
    f32x4 st[2][4] = {};
    __builtin_amdgcn_s_setprio(1);
#pragma unroll
    for (int kk = 0; kk < 2; ++kk)
#pragma unroll
      for (int nf = 0; nf < 4; ++nf) {
        int rk = nf * 16 + lr;
        bf16x8 bk = *(const bf16x8*)(Kc + rk * 128 + (((kk * 4 + lg) ^ (rk & 7)) << 4));
        st[0][nf] = __builtin_amdgcn_mfma_f32_16x16x32_bf16(bk, aq[kk][0], st[0][nf], 0, 0, 0);
        st[1][nf] = __builtin_amdgcn_mfma_f32_16x16x32_bf16(bk, aq[kk][1], st[1][nf], 0, 0, 0);
      }
    __builtin_amdgcn_s_setprio(0);

    // in-register online softmax (lane owns q=lr per mf; k over (nf,r) in-lane + lg cross-lane)
#pragma unroll
    for (int mf = 0; mf < 2; ++mf) {
      float mx = st[mf][0][0];
#pragma unroll
      for (int nf = 0; nf < 4; ++nf)
#pragma unroll
        for (int r = 0; r < 4; ++r) mx = fmaxf(mx, st[mf][nf][r]);
      mx *= 0.125f;
      mx = fmaxf(mx, __shfl_xor(mx, 16));
      mx = fmaxf(mx, __shfl_xor(mx, 32));
      float mnew = m_run[mf], cr = 1.0f;
      if (__any(mx > m_run[mf] + 8.0f)) {       // T13 defer-max
        mnew = fmaxf(m_run[mf], mx);
        cr = __expf(m_run[mf] - mnew);
#pragma unroll
        for (int df = 0; df < 4; ++df) acc[mf][df] *= cr;
      }
      float lsum = 0.0f;
#pragma unroll
      for (int nf = 0; nf < 4; ++nf)
#pragma unroll
        for (int r = 0; r < 4; ++r) {
          float p = __expf(fmaf(st[mf][nf][r], 0.125f, -mnew));
          st[mf][nf][r] = p;
          lsum += p;
        }
      lsum += __shfl_xor(lsum, 16);
      lsum += __shfl_xor(lsum, 32);
      l_run[mf] = l_run[mf] * cr + lsum;
      m_run[mf] = mnew;

      // P^T -> wave-private LDS stripe as P[q][k]
#pragma unroll
      for (int nf = 0; nf < 4; ++nf) {
        int row = mf * 16 + lr;
        bf16x4 pw;
#pragma unroll
        for (int r = 0; r < 4; ++r) pw[r] = (__bf16)st[mf][nf][r];
        int slot = nf * 2 + (lg >> 1);
        *(bf16x4*)(Pw + row * 128 + (((slot ^ (lr & 7)) << 4) | ((lg & 1) * 8))) = pw;
      }
    }

    // O^T += V^T P^T
    __builtin_amdgcn_s_setprio(1);
#pragma unroll
    for (int kk = 0; kk < 2; ++kk) {
      bf16x8 ap[2];
#pragma unroll
      for (int mf = 0; mf < 2; ++mf) {
        int row = mf * 16 + lr;
        ap[mf] = *(const bf16x8*)(Pw + row * 128 + (((kk * 4 + lg) ^ (lr & 7)) << 4));
      }
#pragma unroll
      for (int df = 0; df < 4; ++df) {
        int rv = df * 16 + lr;
        bf16x8 av = *(const bf16x8*)(Vc + rv * 128 + (((kk * 4 + lg) ^ (rv & 7)) << 4));
        acc[0][df] = __builtin_amdgcn_mfma_f32_16x16x32_bf16(av, ap[0], acc[0][df], 0, 0, 0);
        acc[1][df] = __builtin_amdgcn_mfma_f32_16x16x32_bf16(av, ap[1], acc[1][df], 0, 0, 0);
      }
    }
    __builtin_amdgcn_s_setprio(0);

    __syncthreads();                     // all reads of current tiles done
    if (pref) {
      int c = t;
      *(bf16x8*)(Kl + c * 16)        = rK0;
      *(bf16x8*)(Kl + 8192 + c * 16) = rK1;
      *(bf16x8*)(Vl + c * 16)        = rV0;
      *(bf16x8*)(Vl + 8192 + c * 16) = rV1;
      __syncthreads();                   // writes visible
    }
  }

  // ---- merge the two KV-halves (K/V and P regions are dead now) ----
  __syncthreads();
  if (half == 1) {
    char* Ob = smem + qq * 8192;                         // O partial: 8KB per qq
#pragma unroll
    for (int mf = 0; mf < 2; ++mf)
#pragma unroll
      for (int df = 0; df < 4; ++df)
        *(f32x4*)(Ob + (mf * 4 + df) * 1024 + lane * 16) = acc[mf][df];
    if (lg == 0) {
#pragma unroll
      for (int mf = 0; mf < 2; ++mf)
        *(float2*)(smem + 32768 + qq * 1024 + mf * 128 + lr * 8) =
            make_float2(m_run[mf], l_run[mf]);
    }
  }
  __syncthreads();
  if (half == 0) {
    char* Ob = smem + qq * 8192;
    const int b = bh >> 4, h = bh & 15;
#pragma unroll
    for (int mf = 0; mf < 2; ++mf) {
      float2 ml1 = *(const float2*)(smem + 32768 + qq * 1024 + mf * 128 + lr * 8);
      float m = fmaxf(m_run[mf], ml1.x);
      float a0 = __expf(m_run[mf] - m);
      float a1 = __expf(ml1.x - m);
      float linv = 1.0f / (l_run[mf] * a0 + ml1.y * a1);
      int l = q0 + mf * 16 + lr;
#pragma unroll
      for (int df = 0; df < 4; ++df) {
        f32x4 o1 = *(const f32x4*)(Ob + (mf * 4 + df) * 1024 + lane * 16);
        bf16x4 ov;
#pragma unroll
        for (int r = 0; r < 4; ++r)
          ov[r] = (__bf16)((acc[mf][df][r] * a0 + o1[r] * a1) * linv);
        int d0 = df * 16 + lg * 4;
        *(bf16x4*)(ob + ((size_t)(b * 2048 + l)) * 1024 + h * 64 + d0) = ov;
      }
    }
  }
}

// ---------------- launch ----------------
extern "C" void kernel_launch(void* const* d_in, const int* in_sizes, int n_in,
                              void* d_out, int out_size, void* d_ws, size_t ws_size,
                              hipStream_t stream) {
  (void)in_sizes; (void)n_in; (void)out_size; (void)ws_size;
  const float* x    = (const float*)d_in[0];
  const float* Wqkv = (const float*)d_in[1];
  const float* bqkv = (const float*)d_in[2];
  const float* Wout = (const float*)d_in[3];
  const float* bout = (const float*)d_in[4];
  const float* qg   = (const float*)d_in[5];
  const float* kg   = (const float*)d_in[6];

  char* ws = (char*)d_ws;
  __bf16* xb   = (__bf16*)(ws);                 // 4096x1024       (8 MB)
  __bf16* wqb  = (__bf16*)(ws + 8388608);       // 3072x1024       (6 MB)
  __bf16* wob  = (__bf16*)(ws + 14680064);      // 1024x1024       (2 MB)
  __bf16* qbuf = (__bf16*)(ws + 16777216);      // [2][16][2048][64]
  __bf16* kbuf = (__bf16*)(ws + 25165824);
  __bf16* vbuf = (__bf16*)(ws + 33554432);      // V^T: [2][16][64][2048]
  __bf16* aob  = (__bf16*)(ws + 41943040);      // [2][2048][1024]
  float2* rtab = (float2*)(ws + 50331648);      // [2048][32] cos/sin

  prep_kernel<<<8448, 256, 0, stream>>>(x, xb, 1048576, Wqkv, wqb, 786432,
                                        Wout, wob, 262144, rtab);
  gemm_bt<0><<<768, 256, 0, stream>>>(xb, wqb, 1024, 24, bqkv, qbuf, kbuf, vbuf, nullptr,
                                      qg, kg, rtab);
  attn_kernel<<<512, 512, 0, stream>>>(qbuf, kbuf, vbuf, aob);
  gemm_bt<1><<<256, 256, 0, stream>>>(aob, wob, 1024, 8, bout, nullptr, nullptr, nullptr,
                                      (float*)d_out, nullptr, nullptr, nullptr);
}

// Round 8
// 204.204 us; speedup vs baseline: 1.1555x; 1.0507x over previous
//
#include <hip/hip_runtime.h>
#include <hip/hip_bf16.h>

typedef __bf16 bf16x8 __attribute__((ext_vector_type(8)));
typedef __bf16 bf16x4 __attribute__((ext_vector_type(4)));
typedef float  f32x4  __attribute__((ext_vector_type(4)));

#define GLOBAL_AS __attribute__((address_space(1)))
#define LDS_AS    __attribute__((address_space(3)))

__device__ __forceinline__ void glds16(const void* g, void* l) {
  __builtin_amdgcn_global_load_lds((const GLOBAL_AS void*)g, (LDS_AS void*)l, 16, 0, 0);
}

// ---------------- prep: f32->bf16 converts (x, W_qkv, W_out) + RoPE cos/sin table ----------------
__global__ __launch_bounds__(256) void prep_kernel(
    const float* __restrict__ a, __bf16* __restrict__ da, int na4,
    const float* __restrict__ b, __bf16* __restrict__ db, int nb4,
    const float* __restrict__ c, __bf16* __restrict__ dc, int nc4,
    float2* __restrict__ tab) {
  int i = blockIdx.x * 256 + threadIdx.x;
  const float* s; __bf16* d; int j = i;
  if (i < na4) { s = a; d = da; }
  else if ((j = i - na4) < nb4) { s = b; d = db; }
  else if ((j = i - na4 - nb4) < nc4) { s = c; d = dc; }
  else {
    j = i - na4 - nb4 - nc4;
    if (j < 65536) {                     // [l(2048)][j(32)] cos/sin
      int l = j >> 5, jj = j & 31;
      float inv = 1.0f / powf(10000.0f, (float)jj * (1.0f / 32.0f));
      float ang = (float)l * inv;
      tab[j] = make_float2(cosf(ang), sinf(ang));
    }
    return;
  }
  float4 f = ((const float4*)s)[j];
  bf16x4 o;
  o[0] = (__bf16)f.x; o[1] = (__bf16)f.y; o[2] = (__bf16)f.z; o[3] = (__bf16)f.w;
  ((bf16x4*)d)[j] = o;
}

// ---------------- GEMM C = A * B^T (+bias), A[M,K] bf16, B[N,K] bf16 ----------------
// 128x128 tile, BK=64, 4 waves (2x2), 16x16x32 bf16 MFMA, XOR-swizzled LDS (conflict-free),
// 16 K-iters (2 barriers each). 1-D grid + XCD swizzle.
// EPI 0: fused RMSNorm+RoPE -> q/k [b,h,l,d] bf16; v TRANSPOSED [b,h,d,l] bf16.
// EPI 1: d_out f32.
template <int EPI>
__global__ __launch_bounds__(256) void gemm_bt(
    const __bf16* __restrict__ A, const __bf16* __restrict__ Bm, int K, int nbn,
    const float* __restrict__ bias,
    __bf16* __restrict__ qo, __bf16* __restrict__ ko, __bf16* __restrict__ vo,
    float* __restrict__ out,
    const float* __restrict__ qg, const float* __restrict__ kg,
    const float2* __restrict__ tab) {
  __shared__ __bf16 As[128 * 64];
  __shared__ __bf16 Bs[128 * 64];
  const int t = threadIdx.x;
  const int nwg = gridDim.x;
  const int id = blockIdx.x;
  const int swz = (id & 7) * (nwg >> 3) + (id >> 3);
  const int bn = swz % nbn, bm = swz / nbn;
  const int lane = t & 63, w = t >> 6;
  const int wr = w >> 1, wc = w & 1;
  const int lr = lane & 15, lg = lane >> 4;
  const size_t rowA0 = (size_t)bm * 128, rowB0 = (size_t)bn * 128;

  f32x4 acc[4][4] = {};

  for (int k0 = 0; k0 < K; k0 += 64) {
    __syncthreads();
    // stage: 1024 chunks of 16B per matrix; LDS linear, global slot pre-swizzled (involution)
#pragma unroll
    for (int i = 0; i < 4; ++i) {
      int c = t + i * 256;
      int row = c >> 3, sl = c & 7;
      int sp = sl ^ (row & 7);
      glds16(A + (rowA0 + row) * K + k0 + sp * 8, As + c * 8);
      glds16(Bm + (rowB0 + row) * K + k0 + sp * 8, Bs + c * 8);
    }
    __syncthreads();
#pragma unroll
    for (int kk = 0; kk < 2; ++kk) {
      bf16x8 af[4], bfr[4];
#pragma unroll
      for (int i = 0; i < 4; ++i) {
        int ar = wr * 64 + i * 16 + lr;
        int br = wc * 64 + i * 16 + lr;
        af[i]  = *(const bf16x8*)&As[ar * 64 + (((kk * 4 + lg) ^ (ar & 7)) * 8)];
        bfr[i] = *(const bf16x8*)&Bs[br * 64 + (((kk * 4 + lg) ^ (br & 7)) * 8)];
      }
#pragma unroll
      for (int mi = 0; mi < 4; ++mi)
#pragma unroll
        for (int ni = 0; ni < 4; ++ni)
          acc[mi][ni] = __builtin_amdgcn_mfma_f32_16x16x32_bf16(af[mi], bfr[ni], acc[mi][ni], 0, 0, 0);
    }
  }

  // epilogue: C/D layout col=lane&15, row=(lane>>4)*4+reg (m89-verified)
  if constexpr (EPI == 0) {
    const int sect = bn >> 3;                // 0:q 1:k 2:v
    const int h = (bn * 2 + wc) & 15;
    float bbv[4];
#pragma unroll
    for (int ni = 0; ni < 4; ++ni) bbv[ni] = bias[bn * 128 + wc * 64 + ni * 16 + lr];
    if (sect < 2) {
      __bf16* dst = sect ? ko : qo;
      const float* g = sect ? kg : qg;
      float gam[4];
#pragma unroll
      for (int ni = 0; ni < 4; ++ni) gam[ni] = g[ni * 16 + lr];   // d = ni*16+lr
      float ss[4][4];
#pragma unroll
      for (int mi = 0; mi < 4; ++mi)
#pragma unroll
        for (int r = 0; r < 4; ++r) {
          float s = 0.0f;
#pragma unroll
          for (int ni = 0; ni < 4; ++ni) {
            acc[mi][ni][r] += bbv[ni];
            s += acc[mi][ni][r] * acc[mi][ni][r];
          }
          ss[mi][r] = s;
        }
#pragma unroll
      for (int step = 1; step <= 8; step <<= 1)
#pragma unroll
        for (int mi = 0; mi < 4; ++mi)
#pragma unroll
          for (int r = 0; r < 4; ++r)
            ss[mi][r] += __shfl_xor(ss[mi][r], step);
#pragma unroll
      for (int mi = 0; mi < 4; ++mi) {
#pragma unroll
        for (int r = 0; r < 4; ++r) {
          int m = bm * 128 + wr * 64 + mi * 16 + lg * 4 + r;
          int b_ = m >> 11, l = m & 2047;
          float rinv = rsqrtf(ss[mi][r] * (1.0f / 64.0f) + 1e-6f);
          float v0 = acc[mi][0][r] * rinv * gam[0];
          float v1 = acc[mi][1][r] * rinv * gam[1];
          float v2 = acc[mi][2][r] * rinv * gam[2];
          float v3 = acc[mi][3][r] * rinv * gam[3];
          float2 cs0 = tab[l * 32 + lr];
          float2 cs1 = tab[l * 32 + 16 + lr];
          float o0 = v0 * cs0.x - v2 * cs0.y;
          float o2 = v2 * cs0.x + v0 * cs0.y;
          float o1 = v1 * cs1.x - v3 * cs1.y;
          float o3 = v3 * cs1.x + v1 * cs1.y;
          size_t base = ((size_t)(b_ * 16 + h) * 2048 + l) * 64;
          dst[base + lr]      = (__bf16)o0;
          dst[base + 16 + lr] = (__bf16)o1;
          dst[base + 32 + lr] = (__bf16)o2;
          dst[base + 48 + lr] = (__bf16)o3;
        }
      }
    } else {
      // V^T [b,h,d,l]
#pragma unroll
      for (int mi = 0; mi < 4; ++mi) {
#pragma unroll
        for (int ni = 0; ni < 4; ++ni) {
          int d = ni * 16 + lr;
#pragma unroll
          for (int r = 0; r < 4; ++r) {
            int m = bm * 128 + wr * 64 + mi * 16 + lg * 4 + r;
            int b_ = m >> 11, l = m & 2047;
            vo[((size_t)((b_ * 16 + h) * 64 + d)) * 2048 + l] = (__bf16)(acc[mi][ni][r] + bbv[ni]);
          }
        }
      }
    }
  } else {
#pragma unroll
    for (int mi = 0; mi < 4; ++mi) {
      int m0 = bm * 128 + wr * 64 + mi * 16 + lg * 4;
#pragma unroll
      for (int ni = 0; ni < 4; ++ni) {
        int n = bn * 128 + wc * 64 + ni * 16 + lr;
        float bb = bias[n];
#pragma unroll
        for (int r = 0; r < 4; ++r)
          out[(size_t)(m0 + r) * 1024 + n] = acc[mi][ni][r] + bb;
      }
    }
  }
}

// ---------------- flash attention: 8 waves = 4 q-quarters x 2 KV-halves ----------------
// grid 512 (fq,bh via balanced pairing), block 512. KV staged in LDS (shared by all 8 waves),
// each KV-half processes niter = ntiles/2 tiles; halves merged via LDS at the end.
// LDS 64K: K [2][64][64] | V^T [2][64][64] | P stripes 8x4K. 2 blocks/CU -> 4 waves/SIMD.
__global__ __launch_bounds__(512, 4) void attn_kernel(
    const __bf16* __restrict__ qb, const __bf16* __restrict__ kb,
    const __bf16* __restrict__ vT, __bf16* __restrict__ ob) {
  __shared__ char smem[65536];
  char* Kl = smem;                       // [half][64][64] bf16
  char* Vl = smem + 16384;               // [half][64][64] bf16 (V^T rows=d)

  const int id = blockIdx.x;             // 0..511
  const int rank = (id < 256) ? id : 767 - id;   // complementary fq pairing per CU
  const int fq = rank >> 5;
  const int bh = rank & 31;
  const int t = threadIdx.x;
  const int lane = t & 63;
  const int w = t >> 6;                  // 0..7
  const int qq = w & 3;
  const int half = w >> 2;
  const int lr = lane & 15, lg = lane >> 4;
  const size_t hoff = (size_t)bh * (2048 * 64);
  const int q0 = fq * 128 + qq * 32;
  char* Pw = smem + 32768 + w * 4096;    // wave-private P [32][64] bf16

  const int fkS = (fq == 15) ? 2 : 0;
  const int niter = (fq + 1) - (fq == 15 ? 1 : 0);   // tiles per half (ntiles always even)

  // Q fragments direct from global (B-operand: lane holds Q[q0+mf*16+lr][kk*32+lg*8..+8])
  bf16x8 aq[2][2];
#pragma unroll
  for (int kk = 0; kk < 2; ++kk)
#pragma unroll
    for (int mf = 0; mf < 2; ++mf)
      aq[kk][mf] = *(const bf16x8*)(qb + hoff + (size_t)(q0 + mf * 16 + lr) * 64 + kk * 32 + lg * 8);

  // stage tile 0 of both halves (pre-swizzled source, linear LDS dest; 4 glds16/thread)
  {
    int c = t, row = c >> 3, sl = c & 7, sp = sl ^ (row & 7);
    glds16(kb + hoff + (size_t)((fkS) * 64 + row) * 64 + sp * 8,         Kl + c * 16);
    glds16(kb + hoff + (size_t)((fkS + niter) * 64 + row) * 64 + sp * 8, Kl + 8192 + c * 16);
    glds16(vT + hoff + (size_t)row * 2048 + (fkS) * 64 + sp * 8,         Vl + c * 16);
    glds16(vT + hoff + (size_t)row * 2048 + (fkS + niter) * 64 + sp * 8, Vl + 8192 + c * 16);
  }
  __syncthreads();

  f32x4 acc[2][4] = {};                  // O^T accumulator [mf(q)][df(d)]
  float m_run[2] = {-INFINITY, -INFINITY};
  float l_run[2] = {0.0f, 0.0f};

  for (int it = 0; it < niter; ++it) {
    // T14: reg-prefetch next tile of both halves
    const bool pref = (it + 1 < niter);
    bf16x8 rK0, rK1, rV0, rV1;
    if (pref) {
      int c = t, row = c >> 3, sl = c & 7, sp = sl ^ (row & 7);
      rK0 = *(const bf16x8*)(kb + hoff + (size_t)((fkS + it + 1) * 64 + row) * 64 + sp * 8);
      rK1 = *(const bf16x8*)(kb + hoff + (size_t)((fkS + niter + it + 1) * 64 + row) * 64 + sp * 8);
      rV0 = *(const bf16x8*)(vT + hoff + (size_t)row * 2048 + (fkS + it + 1) * 64 + sp * 8);
      rV1 = *(const bf16x8*)(vT + hoff + (size_t)row * 2048 + (fkS + niter + it + 1) * 64 + sp * 8);
    }
    char* Kc = Kl + half * 8192;
    char* Vc = Vl + half * 8192;

    // S^T = K Q^T
    f32x4 st[2][4] = {};
    __builtin_amdgcn_s_setprio(1);
#pragma unroll
    for (int kk = 0; kk < 2; ++kk)
#pragma unroll
      for (int nf = 0; nf < 4; ++nf) {
        int rk = nf * 16 + lr;
        bf16x8 bk = *(const bf16x8*)(Kc + rk * 128 + (((kk * 4 + lg) ^ (rk & 7)) << 4));
        st[0][nf] = __builtin_amdgcn_mfma_f32_16x16x32_bf16(bk, aq[kk][0], st[0][nf], 0, 0, 0);
        st[1][nf] = __builtin_amdgcn_mfma_f32_16x16x32_bf16(bk, aq[kk][1], st[1][nf], 0, 0, 0);
      }
    __builtin_amdgcn_s_setprio(0);

    // in-register online softmax (lane owns q=lr per mf; k over (nf,r) in-lane + lg cross-lane)
#pragma unroll
    for (int mf = 0; mf < 2; ++mf) {
      float mx = st[mf][0][0];
#pragma unroll
      for (int nf = 0; nf < 4; ++nf)
#pragma unroll
        for (int r = 0; r < 4; ++r) mx = fmaxf(mx, st[mf][nf][r]);
      mx *= 0.125f;
      mx = fmaxf(mx, __shfl_xor(mx, 16));
      mx = fmaxf(mx, __shfl_xor(mx, 32));
      float mnew = m_run[mf], cr = 1.0f;
      if (__any(mx > m_run[mf] + 8.0f)) {       // T13 defer-max
        mnew = fmaxf(m_run[mf], mx);
        cr = __expf(m_run[mf] - mnew);
#pragma unroll
        for (int df = 0; df < 4; ++df) acc[mf][df] *= cr;
      }
      float lsum = 0.0f;
#pragma unroll
      for (int nf = 0; nf < 4; ++nf)
#pragma unroll
        for (int r = 0; r < 4; ++r) {
          float p = __expf(fmaf(st[mf][nf][r], 0.125f, -mnew));
          st[mf][nf][r] = p;
          lsum += p;
        }
      lsum += __shfl_xor(lsum, 16);
      lsum += __shfl_xor(lsum, 32);
      l_run[mf] = l_run[mf] * cr + lsum;
      m_run[mf] = mnew;

      // P^T -> wave-private LDS stripe as P[q][k]
#pragma unroll
      for (int nf = 0; nf < 4; ++nf) {
        int row = mf * 16 + lr;
        bf16x4 pw;
#pragma unroll
        for (int r = 0; r < 4; ++r) pw[r] = (__bf16)st[mf][nf][r];
        int slot = nf * 2 + (lg >> 1);
        *(bf16x4*)(Pw + row * 128 + (((slot ^ (lr & 7)) << 4) | ((lg & 1) * 8))) = pw;
      }
    }

    // O^T += V^T P^T
    __builtin_amdgcn_s_setprio(1);
#pragma unroll
    for (int kk = 0; kk < 2; ++kk) {
      bf16x8 ap[2];
#pragma unroll
      for (int mf = 0; mf < 2; ++mf) {
        int row = mf * 16 + lr;
        ap[mf] = *(const bf16x8*)(Pw + row * 128 + (((kk * 4 + lg) ^ (lr & 7)) << 4));
      }
#pragma unroll
      for (int df = 0; df < 4; ++df) {
        int rv = df * 16 + lr;
        bf16x8 av = *(const bf16x8*)(Vc + rv * 128 + (((kk * 4 + lg) ^ (rv & 7)) << 4));
        acc[0][df] = __builtin_amdgcn_mfma_f32_16x16x32_bf16(av, ap[0], acc[0][df], 0, 0, 0);
        acc[1][df] = __builtin_amdgcn_mfma_f32_16x16x32_bf16(av, ap[1], acc[1][df], 0, 0, 0);
      }
    }
    __builtin_amdgcn_s_setprio(0);

    __syncthreads();                     // all reads of current tiles done
    if (pref) {
      int c = t;
      *(bf16x8*)(Kl + c * 16)        = rK0;
      *(bf16x8*)(Kl + 8192 + c * 16) = rK1;
      *(bf16x8*)(Vl + c * 16)        = rV0;
      *(bf16x8*)(Vl + 8192 + c * 16) = rV1;
      __syncthreads();                   // writes visible
    }
  }

  // ---- merge the two KV-halves (K/V and P regions are dead now) ----
  __syncthreads();
  if (half == 1) {
    char* Ob = smem + qq * 8192;                         // O partial: 8KB per qq
#pragma unroll
    for (int mf = 0; mf < 2; ++mf)
#pragma unroll
      for (int df = 0; df < 4; ++df)
        *(f32x4*)(Ob + (mf * 4 + df) * 1024 + lane * 16) = acc[mf][df];
    if (lg == 0) {
#pragma unroll
      for (int mf = 0; mf < 2; ++mf)
        *(float2*)(smem + 32768 + qq * 1024 + mf * 128 + lr * 8) =
            make_float2(m_run[mf], l_run[mf]);
    }
  }
  __syncthreads();
  if (half == 0) {
    char* Ob = smem + qq * 8192;
    const int b = bh >> 4, h = bh & 15;
#pragma unroll
    for (int mf = 0; mf < 2; ++mf) {
      float2 ml1 = *(const float2*)(smem + 32768 + qq * 1024 + mf * 128 + lr * 8);
      float m = fmaxf(m_run[mf], ml1.x);
      float a0 = __expf(m_run[mf] - m);
      float a1 = __expf(ml1.x - m);
      float linv = 1.0f / (l_run[mf] * a0 + ml1.y * a1);
      int l = q0 + mf * 16 + lr;
#pragma unroll
      for (int df = 0; df < 4; ++df) {
        f32x4 o1 = *(const f32x4*)(Ob + (mf * 4 + df) * 1024 + lane * 16);
        bf16x4 ov;
#pragma unroll
        for (int r = 0; r < 4; ++r)
          ov[r] = (__bf16)((acc[mf][df][r] * a0 + o1[r] * a1) * linv);
        int d0 = df * 16 + lg * 4;
        *(bf16x4*)(ob + ((size_t)(b * 2048 + l)) * 1024 + h * 64 + d0) = ov;
      }
    }
  }
}

// ---------------- launch ----------------
extern "C" void kernel_launch(void* const* d_in, const int* in_sizes, int n_in,
                              void* d_out, int out_size, void* d_ws, size_t ws_size,
                              hipStream_t stream) {
  (void)in_sizes; (void)n_in; (void)out_size; (void)ws_size;
  const float* x    = (const float*)d_in[0];
  const float* Wqkv = (const float*)d_in[1];
  const float* bqkv = (const float*)d_in[2];
  const float* Wout = (const float*)d_in[3];
  const float* bout = (const float*)d_in[4];
  const float* qg   = (const float*)d_in[5];
  const float* kg   = (const float*)d_in[6];

  char* ws = (char*)d_ws;
  __bf16* xb   = (__bf16*)(ws);                 // 4096x1024       (8 MB)
  __bf16* wqb  = (__bf16*)(ws + 8388608);       // 3072x1024       (6 MB)
  __bf16* wob  = (__bf16*)(ws + 14680064);      // 1024x1024       (2 MB)
  __bf16* qbuf = (__bf16*)(ws + 16777216);      // [2][16][2048][64]
  __bf16* kbuf = (__bf16*)(ws + 25165824);
  __bf16* vbuf = (__bf16*)(ws + 33554432);      // V^T: [2][16][64][2048]
  __bf16* aob  = (__bf16*)(ws + 41943040);      // [2][2048][1024]
  float2* rtab = (float2*)(ws + 50331648);      // [2048][32] cos/sin

  prep_kernel<<<8448, 256, 0, stream>>>(x, xb, 1048576, Wqkv, wqb, 786432,
                                        Wout, wob, 262144, rtab);
  gemm_bt<0><<<768, 256, 0, stream>>>(xb, wqb, 1024, 24, bqkv, qbuf, kbuf, vbuf, nullptr,
                                      qg, kg, rtab);
  attn_kernel<<<512, 512, 0, stream>>>(qbuf, kbuf, vbuf, aob);
  gemm_bt<1><<<256, 256, 0, stream>>>(aob, wob, 1024, 8, bout, nullptr, nullptr, nullptr,
                                      (float*)d_out, nullptr, nullptr, nullptr);
}

// Round 10
// 198.030 us; speedup vs baseline: 1.1915x; 1.0312x over previous
//
#include <hip/hip_runtime.h>
#include <hip/hip_bf16.h>

typedef __bf16 bf16x8 __attribute__((ext_vector_type(8)));
typedef __bf16 bf16x4 __attribute__((ext_vector_type(4)));
typedef float  f32x4  __attribute__((ext_vector_type(4)));

#define GLOBAL_AS __attribute__((address_space(1)))
#define LDS_AS    __attribute__((address_space(3)))

__device__ __forceinline__ void glds16(const void* g, void* l) {
  __builtin_amdgcn_global_load_lds((const GLOBAL_AS void*)g, (LDS_AS void*)l, 16, 0, 0);
}

// ---------------- prep: f32->bf16 converts (x, W_qkv, W_out) + RoPE cos/sin table ----------------
__global__ __launch_bounds__(256) void prep_kernel(
    const float* __restrict__ a, __bf16* __restrict__ da, int na4,
    const float* __restrict__ b, __bf16* __restrict__ db, int nb4,
    const float* __restrict__ c, __bf16* __restrict__ dc, int nc4,
    float2* __restrict__ tab) {
  int i = blockIdx.x * 256 + threadIdx.x;
  const float* s; __bf16* d; int j = i;
  if (i < na4) { s = a; d = da; }
  else if ((j = i - na4) < nb4) { s = b; d = db; }
  else if ((j = i - na4 - nb4) < nc4) { s = c; d = dc; }
  else {
    j = i - na4 - nb4 - nc4;
    if (j < 65536) {                     // [l(2048)][j(32)] cos/sin
      int l = j >> 5, jj = j & 31;
      float inv = 1.0f / powf(10000.0f, (float)jj * (1.0f / 32.0f));
      float ang = (float)l * inv;
      tab[j] = make_float2(cosf(ang), sinf(ang));
    }
    return;
  }
  float4 f = ((const float4*)s)[j];
  bf16x4 o;
  o[0] = (__bf16)f.x; o[1] = (__bf16)f.y; o[2] = (__bf16)f.z; o[3] = (__bf16)f.w;
  ((bf16x4*)d)[j] = o;
}

// ---------------- GEMM C = A * B^T (+bias), A[M,K] bf16, B[N,K] bf16 ----------------
// 128x128 tile, BK=64, double-buffered LDS (2x32KB), ONE barrier per K-iter:
// STAGE(next) issued before compute(cur); __syncthreads (vmcnt(0) drain) publishes the
// prefetch + releases the read buffer. STAGE dest is LANE-LINEAR (glds16 writes at
// base+lane*16 — rule #21); the XOR swizzle lives on the GLOBAL source address only.
// EPI 0: fused RMSNorm+RoPE -> q/k [b,h,l,d] bf16; v TRANSPOSED [b,h,d,l] bf16.
// EPI 1: d_out f32.
template <int EPI>
__global__ __launch_bounds__(256) void gemm_bt(
    const __bf16* __restrict__ A, const __bf16* __restrict__ Bm, int K, int nbn,
    const float* __restrict__ bias,
    __bf16* __restrict__ qo, __bf16* __restrict__ ko, __bf16* __restrict__ vo,
    float* __restrict__ out,
    const float* __restrict__ qg, const float* __restrict__ kg,
    const float2* __restrict__ tab) {
  __shared__ __bf16 As[2][128 * 64];
  __shared__ __bf16 Bs[2][128 * 64];
  const int t = threadIdx.x;
  const int nwg = gridDim.x;
  const int id = blockIdx.x;
  const int swz = (id & 7) * (nwg >> 3) + (id >> 3);
  const int bn = swz % nbn, bm = swz / nbn;
  const int lane = t & 63, w = t >> 6;
  const int wr = w >> 1, wc = w & 1;
  const int lr = lane & 15, lg = lane >> 4;
  const size_t rowA0 = (size_t)bm * 128, rowB0 = (size_t)bn * 128;

  auto STAGE = [&](int buf, int k0) {
#pragma unroll
    for (int i = 0; i < 4; ++i) {
      int c = t + i * 256;               // lane-linear 16B slots (required by glds16)
      int row = c >> 3, sl = c & 7;
      int sp = sl ^ (row & 7);           // involution pre-swizzle on global source
      glds16(A + (rowA0 + row) * K + k0 + sp * 8, &As[buf][c * 8]);
      glds16(Bm + (rowB0 + row) * K + k0 + sp * 8, &Bs[buf][c * 8]);
    }
  };

  f32x4 acc[4][4] = {};

  STAGE(0, 0);
  __syncthreads();
  int cur = 0;
  for (int k0 = 0; k0 < K; k0 += 64) {
    if (k0 + 64 < K) STAGE(cur ^ 1, k0 + 64);    // prefetch overlaps compute below
#pragma unroll
    for (int kk = 0; kk < 2; ++kk) {
      bf16x8 af[4], bfr[4];
#pragma unroll
      for (int i = 0; i < 4; ++i) {
        int ar = wr * 64 + i * 16 + lr;
        int br = wc * 64 + i * 16 + lr;
        af[i]  = *(const bf16x8*)&As[cur][ar * 64 + (((kk * 4 + lg) ^ (ar & 7)) * 8)];
        bfr[i] = *(const bf16x8*)&Bs[cur][br * 64 + (((kk * 4 + lg) ^ (br & 7)) * 8)];
      }
#pragma unroll
      for (int mi = 0; mi < 4; ++mi)
#pragma unroll
        for (int ni = 0; ni < 4; ++ni)
          acc[mi][ni] = __builtin_amdgcn_mfma_f32_16x16x32_bf16(af[mi], bfr[ni], acc[mi][ni], 0, 0, 0);
    }
    __syncthreads();                             // drains prefetch vmcnt + releases cur
    cur ^= 1;
  }

  // epilogue: C/D layout col=lane&15, row=(lane>>4)*4+reg (m89-verified)
  if constexpr (EPI == 0) {
    const int sect = bn >> 3;                // 0:q 1:k 2:v
    const int h = (bn * 2 + wc) & 15;
    float bbv[4];
#pragma unroll
    for (int ni = 0; ni < 4; ++ni) bbv[ni] = bias[bn * 128 + wc * 64 + ni * 16 + lr];
    if (sect < 2) {
      __bf16* dst = sect ? ko : qo;
      const float* g = sect ? kg : qg;
      float gam[4];
#pragma unroll
      for (int ni = 0; ni < 4; ++ni) gam[ni] = g[ni * 16 + lr];   // d = ni*16+lr
      float ss[4][4];
#pragma unroll
      for (int mi = 0; mi < 4; ++mi)
#pragma unroll
        for (int r = 0; r < 4; ++r) {
          float s = 0.0f;
#pragma unroll
          for (int ni = 0; ni < 4; ++ni) {
            acc[mi][ni][r] += bbv[ni];
            s += acc[mi][ni][r] * acc[mi][ni][r];
          }
          ss[mi][r] = s;
        }
#pragma unroll
      for (int step = 1; step <= 8; step <<= 1)
#pragma unroll
        for (int mi = 0; mi < 4; ++mi)
#pragma unroll
          for (int r = 0; r < 4; ++r)
            ss[mi][r] += __shfl_xor(ss[mi][r], step);
#pragma unroll
      for (int mi = 0; mi < 4; ++mi) {
#pragma unroll
        for (int r = 0; r < 4; ++r) {
          int m = bm * 128 + wr * 64 + mi * 16 + lg * 4 + r;
          int b_ = m >> 11, l = m & 2047;
          float rinv = rsqrtf(ss[mi][r] * (1.0f / 64.0f) + 1e-6f);
          float v0 = acc[mi][0][r] * rinv * gam[0];
          float v1 = acc[mi][1][r] * rinv * gam[1];
          float v2 = acc[mi][2][r] * rinv * gam[2];
          float v3 = acc[mi][3][r] * rinv * gam[3];
          float2 cs0 = tab[l * 32 + lr];
          float2 cs1 = tab[l * 32 + 16 + lr];
          float o0 = v0 * cs0.x - v2 * cs0.y;
          float o2 = v2 * cs0.x + v0 * cs0.y;
          float o1 = v1 * cs1.x - v3 * cs1.y;
          float o3 = v3 * cs1.x + v1 * cs1.y;
          size_t base = ((size_t)(b_ * 16 + h) * 2048 + l) * 64;
          dst[base + lr]      = (__bf16)o0;
          dst[base + 16 + lr] = (__bf16)o1;
          dst[base + 32 + lr] = (__bf16)o2;
          dst[base + 48 + lr] = (__bf16)o3;
        }
      }
    } else {
      // V^T [b,h,d,l]
#pragma unroll
      for (int mi = 0; mi < 4; ++mi) {
#pragma unroll
        for (int ni = 0; ni < 4; ++ni) {
          int d = ni * 16 + lr;
#pragma unroll
          for (int r = 0; r < 4; ++r) {
            int m = bm * 128 + wr * 64 + mi * 16 + lg * 4 + r;
            int b_ = m >> 11, l = m & 2047;
            vo[((size_t)((b_ * 16 + h) * 64 + d)) * 2048 + l] = (__bf16)(acc[mi][ni][r] + bbv[ni]);
          }
        }
      }
    }
  } else {
#pragma unroll
    for (int mi = 0; mi < 4; ++mi) {
      int m0 = bm * 128 + wr * 64 + mi * 16 + lg * 4;
#pragma unroll
      for (int ni = 0; ni < 4; ++ni) {
        int n = bn * 128 + wc * 64 + ni * 16 + lr;
        float bb = bias[n];
#pragma unroll
        for (int r = 0; r < 4; ++r)
          out[(size_t)(m0 + r) * 1024 + n] = acc[mi][ni][r] + bb;
      }
    }
  }
}

// ---------------- flash attention: 8 waves = 4 q-quarters x 2 KV-halves ----------------
// (unchanged from round 8 — control)
__global__ __launch_bounds__(512, 4) void attn_kernel(
    const __bf16* __restrict__ qb, const __bf16* __restrict__ kb,
    const __bf16* __restrict__ vT, __bf16* __restrict__ ob) {
  __shared__ char smem[65536];
  char* Kl = smem;                       // [half][64][64] bf16
  char* Vl = smem + 16384;               // [half][64][64] bf16 (V^T rows=d)

  const int id = blockIdx.x;             // 0..511
  const int rank = (id < 256) ? id : 767 - id;   // complementary fq pairing per CU
  const int fq = rank >> 5;
  const int bh = rank & 31;
  const int t = threadIdx.x;
  const int lane = t & 63;
  const int w = t >> 6;                  // 0..7
  const int qq = w & 3;
  const int half = w >> 2;
  const int lr = lane & 15, lg = lane >> 4;
  const size_t hoff = (size_t)bh * (2048 * 64);
  const int q0 = fq * 128 + qq * 32;
  char* Pw = smem + 32768 + w * 4096;    // wave-private P [32][64] bf16

  const int fkS = (fq == 15) ? 2 : 0;
  const int niter = (fq + 1) - (fq == 15 ? 1 : 0);   // tiles per half (ntiles always even)

  // Q fragments direct from global (B-operand: lane holds Q[q0+mf*16+lr][kk*32+lg*8..+8])
  bf16x8 aq[2][2];
#pragma unroll
  for (int kk = 0; kk < 2; ++kk)
#pragma unroll
    for (int mf = 0; mf < 2; ++mf)
      aq[kk][mf] = *(const bf16x8*)(qb + hoff + (size_t)(q0 + mf * 16 + lr) * 64 + kk * 32 + lg * 8);

  // stage tile 0 of both halves (pre-swizzled source, linear LDS dest; 4 glds16/thread)
  {
    int c = t, row = c >> 3, sl = c & 7, sp = sl ^ (row & 7);
    glds16(kb + hoff + (size_t)((fkS) * 64 + row) * 64 + sp * 8,         Kl + c * 16);
    glds16(kb + hoff + (size_t)((fkS + niter) * 64 + row) * 64 + sp * 8, Kl + 8192 + c * 16);
    glds16(vT + hoff + (size_t)row * 2048 + (fkS) * 64 + sp * 8,         Vl + c * 16);
    glds16(vT + hoff + (size_t)row * 2048 + (fkS + niter) * 64 + sp * 8, Vl + 8192 + c * 16);
  }
  __syncthreads();

  f32x4 acc[2][4] = {};                  // O^T accumulator [mf(q)][df(d)]
  float m_run[2] = {-INFINITY, -INFINITY};
  float l_run[2] = {0.0f, 0.0f};

  for (int it = 0; it < niter; ++it) {
    // T14: reg-prefetch next tile of both halves
    const bool pref = (it + 1 < niter);
    bf16x8 rK0, rK1, rV0, rV1;
    if (pref) {
      int c = t, row = c >> 3, sl = c & 7, sp = sl ^ (row & 7);
      rK0 = *(const bf16x8*)(kb + hoff + (size_t)((fkS + it + 1) * 64 + row) * 64 + sp * 8);
      rK1 = *(const bf16x8*)(kb + hoff + (size_t)((fkS + niter + it + 1) * 64 + row) * 64 + sp * 8);
      rV0 = *(const bf16x8*)(vT + hoff + (size_t)row * 2048 + (fkS + it + 1) * 64 + sp * 8);
      rV1 = *(const bf16x8*)(vT + hoff + (size_t)row * 2048 + (fkS + niter + it + 1) * 64 + sp * 8);
    }
    char* Kc = Kl + half * 8192;
    char* Vc = Vl + half * 8192;

    // S^T = K Q^T
    f32x4 st[2][4] = {};
    __builtin_amdgcn_s_setprio(1);
#pragma unroll
    for (int kk = 0; kk < 2; ++kk)
#pragma unroll
      for (int nf = 0; nf < 4; ++nf) {
        int rk = nf * 16 + lr;
        bf16x8 bk = *(const bf16x8*)(Kc + rk * 128 + (((kk * 4 + lg) ^ (rk & 7)) << 4));
        st[0][nf] = __builtin_amdgcn_mfma_f32_16x16x32_bf16(bk, aq[kk][0], st[0][nf], 0, 0, 0);
        st[1][nf] = __builtin_amdgcn_mfma_f32_16x16x32_bf16(bk, aq[kk][1], st[1][nf], 0, 0, 0);
      }
    __builtin_amdgcn_s_setprio(0);

    // in-register online softmax (lane owns q=lr per mf; k over (nf,r) in-lane + lg cross-lane)
#pragma unroll
    for (int mf = 0; mf < 2; ++mf) {
      float mx = st[mf][0][0];
#pragma unroll
      for (int nf = 0; nf < 4; ++nf)
#pragma unroll
        for (int r = 0; r < 4; ++r) mx = fmaxf(mx, st[mf][nf][r]);
      mx *= 0.125f;
      mx = fmaxf(mx, __shfl_xor(mx, 16));
      mx = fmaxf(mx, __shfl_xor(mx, 32));
      float mnew = m_run[mf], cr = 1.0f;
      if (__any(mx > m_run[mf] + 8.0f)) {       // T13 defer-max
        mnew = fmaxf(m_run[mf], mx);
        cr = __expf(m_run[mf] - mnew);
#pragma unroll
        for (int df = 0; df < 4; ++df) acc[mf][df] *= cr;
      }
      float lsum = 0.0f;
#pragma unroll
      for (int nf = 0; nf < 4; ++nf)
#pragma unroll
        for (int r = 0; r < 4; ++r) {
          float p = __expf(fmaf(st[mf][nf][r], 0.125f, -mnew));
          st[mf][nf][r] = p;
          lsum += p;
        }
      lsum += __shfl_xor(lsum, 16);
      lsum += __shfl_xor(lsum, 32);
      l_run[mf] = l_run[mf] * cr + lsum;
      m_run[mf] = mnew;

      // P^T -> wave-private LDS stripe as P[q][k]
#pragma unroll
      for (int nf = 0; nf < 4; ++nf) {
        int row = mf * 16 + lr;
        bf16x4 pw;
#pragma unroll
        for (int r = 0; r < 4; ++r) pw[r] = (__bf16)st[mf][nf][r];
        int slot = nf * 2 + (lg >> 1);
        *(bf16x4*)(Pw + row * 128 + (((slot ^ (lr & 7)) << 4) | ((lg & 1) * 8))) = pw;
      }
    }

    // O^T += V^T P^T
    __builtin_amdgcn_s_setprio(1);
#pragma unroll
    for (int kk = 0; kk < 2; ++kk) {
      bf16x8 ap[2];
#pragma unroll
      for (int mf = 0; mf < 2; ++mf) {
        int row = mf * 16 + lr;
        ap[mf] = *(const bf16x8*)(Pw + row * 128 + (((kk * 4 + lg) ^ (lr & 7)) << 4));
      }
#pragma unroll
      for (int df = 0; df < 4; ++df) {
        int rv = df * 16 + lr;
        bf16x8 av = *(const bf16x8*)(Vc + rv * 128 + (((kk * 4 + lg) ^ (rv & 7)) << 4));
        acc[0][df] = __builtin_amdgcn_mfma_f32_16x16x32_bf16(av, ap[0], acc[0][df], 0, 0, 0);
        acc[1][df] = __builtin_amdgcn_mfma_f32_16x16x32_bf16(av, ap[1], acc[1][df], 0, 0, 0);
      }
    }
    __builtin_amdgcn_s_setprio(0);

    __syncthreads();                     // all reads of current tiles done
    if (pref) {
      int c = t;
      *(bf16x8*)(Kl + c * 16)        = rK0;
      *(bf16x8*)(Kl + 8192 + c * 16) = rK1;
      *(bf16x8*)(Vl + c * 16)        = rV0;
      *(bf16x8*)(Vl + 8192 + c * 16) = rV1;
      __syncthreads();                   // writes visible
    }
  }

  // ---- merge the two KV-halves (K/V and P regions are dead now) ----
  __syncthreads();
  if (half == 1) {
    char* Ob = smem + qq * 8192;                         // O partial: 8KB per qq
#pragma unroll
    for (int mf = 0; mf < 2; ++mf)
#pragma unroll
      for (int df = 0; df < 4; ++df)
        *(f32x4*)(Ob + (mf * 4 + df) * 1024 + lane * 16) = acc[mf][df];
    if (lg == 0) {
#pragma unroll
      for (int mf = 0; mf < 2; ++mf)
        *(float2*)(smem + 32768 + qq * 1024 + mf * 128 + lr * 8) =
            make_float2(m_run[mf], l_run[mf]);
    }
  }
  __syncthreads();
  if (half == 0) {
    char* Ob = smem + qq * 8192;
    const int b = bh >> 4, h = bh & 15;
#pragma unroll
    for (int mf = 0; mf < 2; ++mf) {
      float2 ml1 = *(const float2*)(smem + 32768 + qq * 1024 + mf * 128 + lr * 8);
      float m = fmaxf(m_run[mf], ml1.x);
      float a0 = __expf(m_run[mf] - m);
      float a1 = __expf(ml1.x - m);
      float linv = 1.0f / (l_run[mf] * a0 + ml1.y * a1);
      int l = q0 + mf * 16 + lr;
#pragma unroll
      for (int df = 0; df < 4; ++df) {
        f32x4 o1 = *(const f32x4*)(Ob + (mf * 4 + df) * 1024 + lane * 16);
        bf16x4 ov;
#pragma unroll
        for (int r = 0; r < 4; ++r)
          ov[r] = (__bf16)((acc[mf][df][r] * a0 + o1[r] * a1) * linv);
        int d0 = df * 16 + lg * 4;
        *(bf16x4*)(ob + ((size_t)(b * 2048 + l)) * 1024 + h * 64 + d0) = ov;
      }
    }
  }
}

// ---------------- launch ----------------
extern "C" void kernel_launch(void* const* d_in, const int* in_sizes, int n_in,
                              void* d_out, int out_size, void* d_ws, size_t ws_size,
                              hipStream_t stream) {
  (void)in_sizes; (void)n_in; (void)out_size; (void)ws_size;
  const float* x    = (const float*)d_in[0];
  const float* Wqkv = (const float*)d_in[1];
  const float* bqkv = (const float*)d_in[2];
  const float* Wout = (const float*)d_in[3];
  const float* bout = (const float*)d_in[4];
  const float* qg   = (const float*)d_in[5];
  const float* kg   = (const float*)d_in[6];

  char* ws = (char*)d_ws;
  __bf16* xb   = (__bf16*)(ws);                 // 4096x1024       (8 MB)
  __bf16* wqb  = (__bf16*)(ws + 8388608);       // 3072x1024       (6 MB)
  __bf16* wob  = (__bf16*)(ws + 14680064);      // 1024x1024       (2 MB)
  __bf16* qbuf = (__bf16*)(ws + 16777216);      // [2][16][2048][64]
  __bf16* kbuf = (__bf16*)(ws + 25165824);
  __bf16* vbuf = (__bf16*)(ws + 33554432);      // V^T: [2][16][64][2048]
  __bf16* aob  = (__bf16*)(ws + 41943040);      // [2][2048][1024]
  float2* rtab = (float2*)(ws + 50331648);      // [2048][32] cos/sin

  prep_kernel<<<8448, 256, 0, stream>>>(x, xb, 1048576, Wqkv, wqb, 786432,
                                        Wout, wob, 262144, rtab);
  gemm_bt<0><<<768, 256, 0, stream>>>(xb, wqb, 1024, 24, bqkv, qbuf, kbuf, vbuf, nullptr,
                                      qg, kg, rtab);
  attn_kernel<<<512, 512, 0, stream>>>(qbuf, kbuf, vbuf, aob);
  gemm_bt<1><<<256, 256, 0, stream>>>(aob, wob, 1024, 8, bout, nullptr, nullptr, nullptr,
                                      (float*)d_out, nullptr, nullptr, nullptr);
}

// Round 11
// 192.560 us; speedup vs baseline: 1.2254x; 1.0284x over previous
//
#include <hip/hip_runtime.h>
#include <hip/hip_bf16.h>

typedef __bf16 bf16x8 __attribute__((ext_vector_type(8)));
typedef __bf16 bf16x4 __attribute__((ext_vector_type(4)));
typedef float  f32x4  __attribute__((ext_vector_type(4)));

#define GLOBAL_AS __attribute__((address_space(1)))
#define LDS_AS    __attribute__((address_space(3)))

__device__ __forceinline__ void glds16(const void* g, void* l) {
  __builtin_amdgcn_global_load_lds((const GLOBAL_AS void*)g, (LDS_AS void*)l, 16, 0, 0);
}

// ---------------- prep: f32->bf16 converts (x, W_qkv, W_out) + RoPE cos/sin table ----------------
__global__ __launch_bounds__(256) void prep_kernel(
    const float* __restrict__ a, __bf16* __restrict__ da, int na4,
    const float* __restrict__ b, __bf16* __restrict__ db, int nb4,
    const float* __restrict__ c, __bf16* __restrict__ dc, int nc4,
    float2* __restrict__ tab) {
  int i = blockIdx.x * 256 + threadIdx.x;
  const float* s; __bf16* d; int j = i;
  if (i < na4) { s = a; d = da; }
  else if ((j = i - na4) < nb4) { s = b; d = db; }
  else if ((j = i - na4 - nb4) < nc4) { s = c; d = dc; }
  else {
    j = i - na4 - nb4 - nc4;
    if (j < 65536) {                     // [l(2048)][j(32)] cos/sin
      int l = j >> 5, jj = j & 31;
      float inv = 1.0f / powf(10000.0f, (float)jj * (1.0f / 32.0f));
      float ang = (float)l * inv;
      tab[j] = make_float2(cosf(ang), sinf(ang));
    }
    return;
  }
  float4 f = ((const float4*)s)[j];
  bf16x4 o;
  o[0] = (__bf16)f.x; o[1] = (__bf16)f.y; o[2] = (__bf16)f.z; o[3] = (__bf16)f.w;
  ((bf16x4*)d)[j] = o;
}

// ---------------- GEMM C = A * B^T (+bias), A[M,K] bf16, B[N,K] bf16 ----------------
// TM x 128 tile, BK=64, single-buffered LDS, 512 threads = 8 waves (WR x WC grid).
// XOR-swizzled LDS reads, lane-linear glds16 staging (swizzle on global source only).
// EPI 0 (TM=128): fused RMSNorm+RoPE -> q/k [b,h,l,d] bf16; v TRANSPOSED [b,h,d,l] bf16.
// EPI 1 (TM=64): d_out f32.
template <int EPI, int TM>
__global__ __launch_bounds__(512) void gemm_bt(
    const __bf16* __restrict__ A, const __bf16* __restrict__ Bm, int K, int nbn,
    const float* __restrict__ bias,
    __bf16* __restrict__ qo, __bf16* __restrict__ ko, __bf16* __restrict__ vo,
    float* __restrict__ out,
    const float* __restrict__ qg, const float* __restrict__ kg,
    const float2* __restrict__ tab) {
  constexpr int WR = TM / 32;          // wave-grid rows (TM=128 -> 4, TM=64 -> 2)
  constexpr int WC = 8 / WR;           // wave-grid cols (2 or 4)
  constexpr int NPW = 128 / WC;        // cols per wave (64 or 32)
  constexpr int NI = NPW / 16;         // n-frags per wave (4 or 2)
  constexpr int ACH = TM * 8;          // A 16B-chunks (multiple of 512)
  __shared__ __bf16 As[TM * 64];
  __shared__ __bf16 Bs[128 * 64];
  const int t = threadIdx.x;
  const int nwg = gridDim.x;
  const int id = blockIdx.x;
  const int swz = (id & 7) * (nwg >> 3) + (id >> 3);
  const int bn = swz % nbn, bm = swz / nbn;
  const int lane = t & 63, w = t >> 6;
  const int wr = w / WC, wc = w % WC;
  const int lr = lane & 15, lg = lane >> 4;
  const size_t rowA0 = (size_t)bm * TM, rowB0 = (size_t)bn * 128;

  f32x4 acc[2][NI] = {};

  for (int k0 = 0; k0 < K; k0 += 64) {
    __syncthreads();
    // stage: lane-linear 16B slots (glds16 writes base+lane*16 — rule #21);
    // each 512-chunk pass is uniformly A or B since ACH % 512 == 0.
#pragma unroll
    for (int c0 = 0; c0 < ACH + 1024; c0 += 512) {
      int c = c0 + t;
      if (c0 < ACH) {
        int row = c >> 3, sl = c & 7, sp = sl ^ (row & 7);
        glds16(A + (rowA0 + row) * K + k0 + sp * 8, As + c * 8);
      } else {
        int c2 = c - ACH;
        int row = c2 >> 3, sl = c2 & 7, sp = sl ^ (row & 7);
        glds16(Bm + (rowB0 + row) * K + k0 + sp * 8, Bs + c2 * 8);
      }
    }
    __syncthreads();
#pragma unroll
    for (int kk = 0; kk < 2; ++kk) {
      bf16x8 af[2], bfr[NI];
#pragma unroll
      for (int i = 0; i < 2; ++i) {
        int ar = wr * 32 + i * 16 + lr;
        af[i] = *(const bf16x8*)&As[ar * 64 + (((kk * 4 + lg) ^ (ar & 7)) * 8)];
      }
#pragma unroll
      for (int i = 0; i < NI; ++i) {
        int br = wc * NPW + i * 16 + lr;
        bfr[i] = *(const bf16x8*)&Bs[br * 64 + (((kk * 4 + lg) ^ (br & 7)) * 8)];
      }
#pragma unroll
      for (int mi = 0; mi < 2; ++mi)
#pragma unroll
        for (int ni = 0; ni < NI; ++ni)
          acc[mi][ni] = __builtin_amdgcn_mfma_f32_16x16x32_bf16(af[mi], bfr[ni], acc[mi][ni], 0, 0, 0);
    }
  }

  // epilogue: C/D layout col=lane&15, row=(lane>>4)*4+reg (m89-verified)
  if constexpr (EPI == 0) {
    // TM=128, WC=2: wave col-block = one whole head (64)
    const int sect = bn >> 3;                // 0:q 1:k 2:v
    const int h = (bn * 2 + wc) & 15;
    float bbv[NI];
#pragma unroll
    for (int ni = 0; ni < NI; ++ni) bbv[ni] = bias[bn * 128 + wc * NPW + ni * 16 + lr];
    if (sect < 2) {
      __bf16* dst = sect ? ko : qo;
      const float* g = sect ? kg : qg;
      float gam[NI];
#pragma unroll
      for (int ni = 0; ni < NI; ++ni) gam[ni] = g[ni * 16 + lr];   // d = ni*16+lr
      float ss[2][4];
#pragma unroll
      for (int mi = 0; mi < 2; ++mi)
#pragma unroll
        for (int r = 0; r < 4; ++r) {
          float s = 0.0f;
#pragma unroll
          for (int ni = 0; ni < NI; ++ni) {
            acc[mi][ni][r] += bbv[ni];
            s += acc[mi][ni][r] * acc[mi][ni][r];
          }
          ss[mi][r] = s;
        }
#pragma unroll
      for (int step = 1; step <= 8; step <<= 1)
#pragma unroll
        for (int mi = 0; mi < 2; ++mi)
#pragma unroll
          for (int r = 0; r < 4; ++r)
            ss[mi][r] += __shfl_xor(ss[mi][r], step);
#pragma unroll
      for (int mi = 0; mi < 2; ++mi) {
#pragma unroll
        for (int r = 0; r < 4; ++r) {
          int m = bm * TM + wr * 32 + mi * 16 + lg * 4 + r;
          int b_ = m >> 11, l = m & 2047;
          float rinv = rsqrtf(ss[mi][r] * (1.0f / 64.0f) + 1e-6f);
          float v0 = acc[mi][0][r] * rinv * gam[0];
          float v1 = acc[mi][1][r] * rinv * gam[1];
          float v2 = acc[mi][2][r] * rinv * gam[2];
          float v3 = acc[mi][3][r] * rinv * gam[3];
          float2 cs0 = tab[l * 32 + lr];
          float2 cs1 = tab[l * 32 + 16 + lr];
          float o0 = v0 * cs0.x - v2 * cs0.y;
          float o2 = v2 * cs0.x + v0 * cs0.y;
          float o1 = v1 * cs1.x - v3 * cs1.y;
          float o3 = v3 * cs1.x + v1 * cs1.y;
          size_t base = ((size_t)(b_ * 16 + h) * 2048 + l) * 64;
          dst[base + lr]      = (__bf16)o0;
          dst[base + 16 + lr] = (__bf16)o1;
          dst[base + 32 + lr] = (__bf16)o2;
          dst[base + 48 + lr] = (__bf16)o3;
        }
      }
    } else {
      // V^T [b,h,d,l]
#pragma unroll
      for (int mi = 0; mi < 2; ++mi) {
#pragma unroll
        for (int ni = 0; ni < NI; ++ni) {
          int d = ni * 16 + lr;
#pragma unroll
          for (int r = 0; r < 4; ++r) {
            int m = bm * TM + wr * 32 + mi * 16 + lg * 4 + r;
            int b_ = m >> 11, l = m & 2047;
            vo[((size_t)((b_ * 16 + h) * 64 + d)) * 2048 + l] = (__bf16)(acc[mi][ni][r] + bbv[ni]);
          }
        }
      }
    }
  } else {
#pragma unroll
    for (int mi = 0; mi < 2; ++mi) {
      int m0 = bm * TM + wr * 32 + mi * 16 + lg * 4;
#pragma unroll
      for (int ni = 0; ni < NI; ++ni) {
        int n = bn * 128 + wc * NPW + ni * 16 + lr;
        float bb = bias[n];
#pragma unroll
        for (int r = 0; r < 4; ++r)
          out[(size_t)(m0 + r) * 1024 + n] = acc[mi][ni][r] + bb;
      }
    }
  }
}

// ---------------- flash attention: 8 waves = 4 q-quarters x 2 KV-halves ----------------
// (unchanged — control)
__global__ __launch_bounds__(512, 4) void attn_kernel(
    const __bf16* __restrict__ qb, const __bf16* __restrict__ kb,
    const __bf16* __restrict__ vT, __bf16* __restrict__ ob) {
  __shared__ char smem[65536];
  char* Kl = smem;                       // [half][64][64] bf16
  char* Vl = smem + 16384;               // [half][64][64] bf16 (V^T rows=d)

  const int id = blockIdx.x;             // 0..511
  const int rank = (id < 256) ? id : 767 - id;   // complementary fq pairing per CU
  const int fq = rank >> 5;
  const int bh = rank & 31;
  const int t = threadIdx.x;
  const int lane = t & 63;
  const int w = t >> 6;                  // 0..7
  const int qq = w & 3;
  const int half = w >> 2;
  const int lr = lane & 15, lg = lane >> 4;
  const size_t hoff = (size_t)bh * (2048 * 64);
  const int q0 = fq * 128 + qq * 32;
  char* Pw = smem + 32768 + w * 4096;    // wave-private P [32][64] bf16

  const int fkS = (fq == 15) ? 2 : 0;
  const int niter = (fq + 1) - (fq == 15 ? 1 : 0);   // tiles per half (ntiles always even)

  // Q fragments direct from global (B-operand: lane holds Q[q0+mf*16+lr][kk*32+lg*8..+8])
  bf16x8 aq[2][2];
#pragma unroll
  for (int kk = 0; kk < 2; ++kk)
#pragma unroll
    for (int mf = 0; mf < 2; ++mf)
      aq[kk][mf] = *(const bf16x8*)(qb + hoff + (size_t)(q0 + mf * 16 + lr) * 64 + kk * 32 + lg * 8);

  // stage tile 0 of both halves (pre-swizzled source, linear LDS dest; 4 glds16/thread)
  {
    int c = t, row = c >> 3, sl = c & 7, sp = sl ^ (row & 7);
    glds16(kb + hoff + (size_t)((fkS) * 64 + row) * 64 + sp * 8,         Kl + c * 16);
    glds16(kb + hoff + (size_t)((fkS + niter) * 64 + row) * 64 + sp * 8, Kl + 8192 + c * 16);
    glds16(vT + hoff + (size_t)row * 2048 + (fkS) * 64 + sp * 8,         Vl + c * 16);
    glds16(vT + hoff + (size_t)row * 2048 + (fkS + niter) * 64 + sp * 8, Vl + 8192 + c * 16);
  }
  __syncthreads();

  f32x4 acc[2][4] = {};                  // O^T accumulator [mf(q)][df(d)]
  float m_run[2] = {-INFINITY, -INFINITY};
  float l_run[2] = {0.0f, 0.0f};

  for (int it = 0; it < niter; ++it) {
    // T14: reg-prefetch next tile of both halves
    const bool pref = (it + 1 < niter);
    bf16x8 rK0, rK1, rV0, rV1;
    if (pref) {
      int c = t, row = c >> 3, sl = c & 7, sp = sl ^ (row & 7);
      rK0 = *(const bf16x8*)(kb + hoff + (size_t)((fkS + it + 1) * 64 + row) * 64 + sp * 8);
      rK1 = *(const bf16x8*)(kb + hoff + (size_t)((fkS + niter + it + 1) * 64 + row) * 64 + sp * 8);
      rV0 = *(const bf16x8*)(vT + hoff + (size_t)row * 2048 + (fkS + it + 1) * 64 + sp * 8);
      rV1 = *(const bf16x8*)(vT + hoff + (size_t)row * 2048 + (fkS + niter + it + 1) * 64 + sp * 8);
    }
    char* Kc = Kl + half * 8192;
    char* Vc = Vl + half * 8192;

    // S^T = K Q^T
    f32x4 st[2][4] = {};
    __builtin_amdgcn_s_setprio(1);
#pragma unroll
    for (int kk = 0; kk < 2; ++kk)
#pragma unroll
      for (int nf = 0; nf < 4; ++nf) {
        int rk = nf * 16 + lr;
        bf16x8 bk = *(const bf16x8*)(Kc + rk * 128 + (((kk * 4 + lg) ^ (rk & 7)) << 4));
        st[0][nf] = __builtin_amdgcn_mfma_f32_16x16x32_bf16(bk, aq[kk][0], st[0][nf], 0, 0, 0);
        st[1][nf] = __builtin_amdgcn_mfma_f32_16x16x32_bf16(bk, aq[kk][1], st[1][nf], 0, 0, 0);
      }
    __builtin_amdgcn_s_setprio(0);

    // in-register online softmax (lane owns q=lr per mf; k over (nf,r) in-lane + lg cross-lane)
#pragma unroll
    for (int mf = 0; mf < 2; ++mf) {
      float mx = st[mf][0][0];
#pragma unroll
      for (int nf = 0; nf < 4; ++nf)
#pragma unroll
        for (int r = 0; r < 4; ++r) mx = fmaxf(mx, st[mf][nf][r]);
      mx *= 0.125f;
      mx = fmaxf(mx, __shfl_xor(mx, 16));
      mx = fmaxf(mx, __shfl_xor(mx, 32));
      float mnew = m_run[mf], cr = 1.0f;
      if (__any(mx > m_run[mf] + 8.0f)) {       // T13 defer-max
        mnew = fmaxf(m_run[mf], mx);
        cr = __expf(m_run[mf] - mnew);
#pragma unroll
        for (int df = 0; df < 4; ++df) acc[mf][df] *= cr;
      }
      float lsum = 0.0f;
#pragma unroll
      for (int nf = 0; nf < 4; ++nf)
#pragma unroll
        for (int r = 0; r < 4; ++r) {
          float p = __expf(fmaf(st[mf][nf][r], 0.125f, -mnew));
          st[mf][nf][r] = p;
          lsum += p;
        }
      lsum += __shfl_xor(lsum, 16);
      lsum += __shfl_xor(lsum, 32);
      l_run[mf] = l_run[mf] * cr + lsum;
      m_run[mf] = mnew;

      // P^T -> wave-private LDS stripe as P[q][k]
#pragma unroll
      for (int nf = 0; nf < 4; ++nf) {
        int row = mf * 16 + lr;
        bf16x4 pw;
#pragma unroll
        for (int r = 0; r < 4; ++r) pw[r] = (__bf16)st[mf][nf][r];
        int slot = nf * 2 + (lg >> 1);
        *(bf16x4*)(Pw + row * 128 + (((slot ^ (lr & 7)) << 4) | ((lg & 1) * 8))) = pw;
      }
    }

    // O^T += V^T P^T
    __builtin_amdgcn_s_setprio(1);
#pragma unroll
    for (int kk = 0; kk < 2; ++kk) {
      bf16x8 ap[2];
#pragma unroll
      for (int mf = 0; mf < 2; ++mf) {
        int row = mf * 16 + lr;
        ap[mf] = *(const bf16x8*)(Pw + row * 128 + (((kk * 4 + lg) ^ (lr & 7)) << 4));
      }
#pragma unroll
      for (int df = 0; df < 4; ++df) {
        int rv = df * 16 + lr;
        bf16x8 av = *(const bf16x8*)(Vc + rv * 128 + (((kk * 4 + lg) ^ (rv & 7)) << 4));
        acc[0][df] = __builtin_amdgcn_mfma_f32_16x16x32_bf16(av, ap[0], acc[0][df], 0, 0, 0);
        acc[1][df] = __builtin_amdgcn_mfma_f32_16x16x32_bf16(av, ap[1], acc[1][df], 0, 0, 0);
      }
    }
    __builtin_amdgcn_s_setprio(0);

    __syncthreads();                     // all reads of current tiles done
    if (pref) {
      int c = t;
      *(bf16x8*)(Kl + c * 16)        = rK0;
      *(bf16x8*)(Kl + 8192 + c * 16) = rK1;
      *(bf16x8*)(Vl + c * 16)        = rV0;
      *(bf16x8*)(Vl + 8192 + c * 16) = rV1;
      __syncthreads();                   // writes visible
    }
  }

  // ---- merge the two KV-halves (K/V and P regions are dead now) ----
  __syncthreads();
  if (half == 1) {
    char* Ob = smem + qq * 8192;                         // O partial: 8KB per qq
#pragma unroll
    for (int mf = 0; mf < 2; ++mf)
#pragma unroll
      for (int df = 0; df < 4; ++df)
        *(f32x4*)(Ob + (mf * 4 + df) * 1024 + lane * 16) = acc[mf][df];
    if (lg == 0) {
#pragma unroll
      for (int mf = 0; mf < 2; ++mf)
        *(float2*)(smem + 32768 + qq * 1024 + mf * 128 + lr * 8) =
            make_float2(m_run[mf], l_run[mf]);
    }
  }
  __syncthreads();
  if (half == 0) {
    char* Ob = smem + qq * 8192;
    const int b = bh >> 4, h = bh & 15;
#pragma unroll
    for (int mf = 0; mf < 2; ++mf) {
      float2 ml1 = *(const float2*)(smem + 32768 + qq * 1024 + mf * 128 + lr * 8);
      float m = fmaxf(m_run[mf], ml1.x);
      float a0 = __expf(m_run[mf] - m);
      float a1 = __expf(ml1.x - m);
      float linv = 1.0f / (l_run[mf] * a0 + ml1.y * a1);
      int l = q0 + mf * 16 + lr;
#pragma unroll
      for (int df = 0; df < 4; ++df) {
        f32x4 o1 = *(const f32x4*)(Ob + (mf * 4 + df) * 1024 + lane * 16);
        bf16x4 ov;
#pragma unroll
        for (int r = 0; r < 4; ++r)
          ov[r] = (__bf16)((acc[mf][df][r] * a0 + o1[r] * a1) * linv);
        int d0 = df * 16 + lg * 4;
        *(bf16x4*)(ob + ((size_t)(b * 2048 + l)) * 1024 + h * 64 + d0) = ov;
      }
    }
  }
}

// ---------------- launch ----------------
extern "C" void kernel_launch(void* const* d_in, const int* in_sizes, int n_in,
                              void* d_out, int out_size, void* d_ws, size_t ws_size,
                              hipStream_t stream) {
  (void)in_sizes; (void)n_in; (void)out_size; (void)ws_size;
  const float* x    = (const float*)d_in[0];
  const float* Wqkv = (const float*)d_in[1];
  const float* bqkv = (const float*)d_in[2];
  const float* Wout = (const float*)d_in[3];
  const float* bout = (const float*)d_in[4];
  const float* qg   = (const float*)d_in[5];
  const float* kg   = (const float*)d_in[6];

  char* ws = (char*)d_ws;
  __bf16* xb   = (__bf16*)(ws);                 // 4096x1024       (8 MB)
  __bf16* wqb  = (__bf16*)(ws + 8388608);       // 3072x1024       (6 MB)
  __bf16* wob  = (__bf16*)(ws + 14680064);      // 1024x1024       (2 MB)
  __bf16* qbuf = (__bf16*)(ws + 16777216);      // [2][16][2048][64]
  __bf16* kbuf = (__bf16*)(ws + 25165824);
  __bf16* vbuf = (__bf16*)(ws + 33554432);      // V^T: [2][16][64][2048]
  __bf16* aob  = (__bf16*)(ws + 41943040);      // [2][2048][1024]
  float2* rtab = (float2*)(ws + 50331648);      // [2048][32] cos/sin

  prep_kernel<<<8448, 256, 0, stream>>>(x, xb, 1048576, Wqkv, wqb, 786432,
                                        Wout, wob, 262144, rtab);
  gemm_bt<0, 128><<<768, 512, 0, stream>>>(xb, wqb, 1024, 24, bqkv, qbuf, kbuf, vbuf, nullptr,
                                           qg, kg, rtab);
  attn_kernel<<<512, 512, 0, stream>>>(qbuf, kbuf, vbuf, aob);
  gemm_bt<1, 64><<<512, 512, 0, stream>>>(aob, wob, 1024, 8, bout, nullptr, nullptr, nullptr,
                                          (float*)d_out, nullptr, nullptr, nullptr);
}

// Round 12
// 187.519 us; speedup vs baseline: 1.2583x; 1.0269x over previous
//
#include <hip/hip_runtime.h>
#include <hip/hip_bf16.h>

typedef __bf16 bf16x8 __attribute__((ext_vector_type(8)));
typedef __bf16 bf16x4 __attribute__((ext_vector_type(4)));
typedef float  f32x4  __attribute__((ext_vector_type(4)));

#define GLOBAL_AS __attribute__((address_space(1)))
#define LDS_AS    __attribute__((address_space(3)))

__device__ __forceinline__ void glds16(const void* g, void* l) {
  __builtin_amdgcn_global_load_lds((const GLOBAL_AS void*)g, (LDS_AS void*)l, 16, 0, 0);
}

// ---------------- prep: f32->bf16 converts (x, W_qkv, W_out) + RoPE cos/sin table ----------------
__global__ __launch_bounds__(256) void prep_kernel(
    const float* __restrict__ a, __bf16* __restrict__ da, int na4,
    const float* __restrict__ b, __bf16* __restrict__ db, int nb4,
    const float* __restrict__ c, __bf16* __restrict__ dc, int nc4,
    float2* __restrict__ tab) {
  int i = blockIdx.x * 256 + threadIdx.x;
  const float* s; __bf16* d; int j = i;
  if (i < na4) { s = a; d = da; }
  else if ((j = i - na4) < nb4) { s = b; d = db; }
  else if ((j = i - na4 - nb4) < nc4) { s = c; d = dc; }
  else {
    j = i - na4 - nb4 - nc4;
    if (j < 65536) {                     // [l(2048)][j(32)] cos/sin
      int l = j >> 5, jj = j & 31;
      float inv = 1.0f / powf(10000.0f, (float)jj * (1.0f / 32.0f));
      float ang = (float)l * inv;
      tab[j] = make_float2(cosf(ang), sinf(ang));
    }
    return;
  }
  float4 f = ((const float4*)s)[j];
  bf16x4 o;
  o[0] = (__bf16)f.x; o[1] = (__bf16)f.y; o[2] = (__bf16)f.z; o[3] = (__bf16)f.w;
  ((bf16x4*)d)[j] = o;
}

// ---------------- GEMM C = A * B^T (+bias), A[M,K] bf16, B[N,K] bf16 ----------------
// TM x 128 tile, BK=32, 3-deep LDS ring with COUNTED vmcnt (T4): at iter i wait vmcnt(PER)
// so stage(i) has landed while stage(i+1) stays in flight; raw s_barrier (no drain);
// stage(i+2) issued after the barrier. Chunk involution c = row*4 + (sl^((row>>1)&3))
// gives conflict-free ds_read_b128 AND lane-linear (rule #21) coalesced glds16 staging.
// 512 threads = 8 waves. EPI 0 (TM=128): fused RMSNorm+RoPE epilogue; EPI 1 (TM=64): f32 out.
template <int EPI, int TM>
__global__ __launch_bounds__(512) void gemm_bt(
    const __bf16* __restrict__ A, const __bf16* __restrict__ Bm, int K, int nbn,
    const float* __restrict__ bias,
    __bf16* __restrict__ qo, __bf16* __restrict__ ko, __bf16* __restrict__ vo,
    float* __restrict__ out,
    const float* __restrict__ qg, const float* __restrict__ kg,
    const float2* __restrict__ tab) {
  constexpr int WR = TM / 32;          // wave-grid rows (4 or 2)
  constexpr int WC = 8 / WR;           // wave-grid cols (2 or 4)
  constexpr int NPW = 128 / WC;        // cols per wave (64 or 32)
  constexpr int NI = NPW / 16;         // n-frags per wave (4 or 2)
  constexpr int ACH = TM * 4;          // A 16B-chunks per stage (BK=32: 4 slots/row)
  constexpr int BCH = 512;             // B 16B-chunks per stage
  __shared__ __bf16 As[3][TM * 32];
  __shared__ __bf16 Bs[3][128 * 32];
  const int t = threadIdx.x;
  const int nwg = gridDim.x;
  const int id = blockIdx.x;
  const int swz = (id & 7) * (nwg >> 3) + (id >> 3);
  const int bn = swz % nbn, bm = swz / nbn;
  const int lane = t & 63, w = t >> 6;
  const int wr = w / WC, wc = w % WC;
  const int lr = lane & 15, lg = lane >> 4;
  const size_t rowA0 = (size_t)bm * TM, rowB0 = (size_t)bn * 128;

  auto STAGE = [&](int buf, int k0) {
#pragma unroll
    for (int c0 = 0; c0 < ACH + BCH; c0 += 512) {
      int c = c0 + t;
      if (c < ACH) {
        int row = c >> 2, q = c & 3, sl = q ^ ((row >> 1) & 3);
        glds16(A + (rowA0 + row) * K + k0 + sl * 8, &As[buf][c * 8]);
      } else if (c < ACH + BCH) {
        int c2 = c - ACH;
        int row = c2 >> 2, q = c2 & 3, sl = q ^ ((row >> 1) & 3);
        glds16(Bm + (rowB0 + row) * K + k0 + sl * 8, &Bs[buf][c2 * 8]);
      }
    }
  };

  f32x4 acc[2][NI] = {};

  STAGE(0, 0);
  STAGE(1, 32);
  const int niter = K >> 5;
  int cur = 0;
  for (int i = 0; i < niter; ++i) {
    // counted wait: stage(i) landed, stage(i+1) stays in flight (per-wave op counts)
    if (i + 1 < niter) {
      if (TM == 64 && w >= 4) asm volatile("s_waitcnt vmcnt(1)" ::: "memory");
      else                    asm volatile("s_waitcnt vmcnt(2)" ::: "memory");
    } else {
      asm volatile("s_waitcnt vmcnt(0)" ::: "memory");
    }
    __builtin_amdgcn_s_barrier();
    asm volatile("" ::: "memory");       // fence compiler load motion across barrier

    bf16x8 af[2], bfr[NI];
#pragma unroll
    for (int mi = 0; mi < 2; ++mi) {
      int ar = wr * 32 + mi * 16 + lr;
      af[mi] = *(const bf16x8*)&As[cur][ar * 32 + ((lg ^ ((ar >> 1) & 3)) * 8)];
    }
#pragma unroll
    for (int ni = 0; ni < NI; ++ni) {
      int br = wc * NPW + ni * 16 + lr;
      bfr[ni] = *(const bf16x8*)&Bs[cur][br * 32 + ((lg ^ ((br >> 1) & 3)) * 8)];
    }

    if (i + 2 < niter) {                 // stage 2-ahead into buf[(i+2)%3] (== buf[(i-1)%3])
      int nxt = cur + 2; if (nxt >= 3) nxt -= 3;
      STAGE(nxt, (i + 2) << 5);
    }

#pragma unroll
    for (int mi = 0; mi < 2; ++mi)
#pragma unroll
      for (int ni = 0; ni < NI; ++ni)
        acc[mi][ni] = __builtin_amdgcn_mfma_f32_16x16x32_bf16(af[mi], bfr[ni], acc[mi][ni], 0, 0, 0);

    ++cur; if (cur == 3) cur = 0;
  }

  // epilogue: C/D layout col=lane&15, row=(lane>>4)*4+reg (m89-verified)
  if constexpr (EPI == 0) {
    const int sect = bn >> 3;                // 0:q 1:k 2:v
    const int h = (bn * 2 + wc) & 15;
    float bbv[NI];
#pragma unroll
    for (int ni = 0; ni < NI; ++ni) bbv[ni] = bias[bn * 128 + wc * NPW + ni * 16 + lr];
    if (sect < 2) {
      __bf16* dst = sect ? ko : qo;
      const float* g = sect ? kg : qg;
      float gam[NI];
#pragma unroll
      for (int ni = 0; ni < NI; ++ni) gam[ni] = g[ni * 16 + lr];   // d = ni*16+lr
      float ss[2][4];
#pragma unroll
      for (int mi = 0; mi < 2; ++mi)
#pragma unroll
        for (int r = 0; r < 4; ++r) {
          float s = 0.0f;
#pragma unroll
          for (int ni = 0; ni < NI; ++ni) {
            acc[mi][ni][r] += bbv[ni];
            s += acc[mi][ni][r] * acc[mi][ni][r];
          }
          ss[mi][r] = s;
        }
#pragma unroll
      for (int step = 1; step <= 8; step <<= 1)
#pragma unroll
        for (int mi = 0; mi < 2; ++mi)
#pragma unroll
          for (int r = 0; r < 4; ++r)
            ss[mi][r] += __shfl_xor(ss[mi][r], step);
#pragma unroll
      for (int mi = 0; mi < 2; ++mi) {
#pragma unroll
        for (int r = 0; r < 4; ++r) {
          int m = bm * TM + wr * 32 + mi * 16 + lg * 4 + r;
          int b_ = m >> 11, l = m & 2047;
          float rinv = rsqrtf(ss[mi][r] * (1.0f / 64.0f) + 1e-6f);
          float v0 = acc[mi][0][r] * rinv * gam[0];
          float v1 = acc[mi][1][r] * rinv * gam[1];
          float v2 = acc[mi][2][r] * rinv * gam[2];
          float v3 = acc[mi][3][r] * rinv * gam[3];
          float2 cs0 = tab[l * 32 + lr];
          float2 cs1 = tab[l * 32 + 16 + lr];
          float o0 = v0 * cs0.x - v2 * cs0.y;
          float o2 = v2 * cs0.x + v0 * cs0.y;
          float o1 = v1 * cs1.x - v3 * cs1.y;
          float o3 = v3 * cs1.x + v1 * cs1.y;
          size_t base = ((size_t)(b_ * 16 + h) * 2048 + l) * 64;
          dst[base + lr]      = (__bf16)o0;
          dst[base + 16 + lr] = (__bf16)o1;
          dst[base + 32 + lr] = (__bf16)o2;
          dst[base + 48 + lr] = (__bf16)o3;
        }
      }
    } else {
      // V^T [b,h,d,l]
#pragma unroll
      for (int mi = 0; mi < 2; ++mi) {
#pragma unroll
        for (int ni = 0; ni < NI; ++ni) {
          int d = ni * 16 + lr;
#pragma unroll
          for (int r = 0; r < 4; ++r) {
            int m = bm * TM + wr * 32 + mi * 16 + lg * 4 + r;
            int b_ = m >> 11, l = m & 2047;
            vo[((size_t)((b_ * 16 + h) * 64 + d)) * 2048 + l] = (__bf16)(acc[mi][ni][r] + bbv[ni]);
          }
        }
      }
    }
  } else {
#pragma unroll
    for (int mi = 0; mi < 2; ++mi) {
      int m0 = bm * TM + wr * 32 + mi * 16 + lg * 4;
#pragma unroll
      for (int ni = 0; ni < NI; ++ni) {
        int n = bn * 128 + wc * NPW + ni * 16 + lr;
        float bb = bias[n];
#pragma unroll
        for (int r = 0; r < 4; ++r)
          out[(size_t)(m0 + r) * 1024 + n] = acc[mi][ni][r] + bb;
      }
    }
  }
}

// ---------------- flash attention: 8 waves = 4 q-quarters x 2 KV-halves ----------------
// (unchanged — control)
__global__ __launch_bounds__(512, 4) void attn_kernel(
    const __bf16* __restrict__ qb, const __bf16* __restrict__ kb,
    const __bf16* __restrict__ vT, __bf16* __restrict__ ob) {
  __shared__ char smem[65536];
  char* Kl = smem;                       // [half][64][64] bf16
  char* Vl = smem + 16384;               // [half][64][64] bf16 (V^T rows=d)

  const int id = blockIdx.x;             // 0..511
  const int rank = (id < 256) ? id : 767 - id;   // complementary fq pairing per CU
  const int fq = rank >> 5;
  const int bh = rank & 31;
  const int t = threadIdx.x;
  const int lane = t & 63;
  const int w = t >> 6;                  // 0..7
  const int qq = w & 3;
  const int half = w >> 2;
  const int lr = lane & 15, lg = lane >> 4;
  const size_t hoff = (size_t)bh * (2048 * 64);
  const int q0 = fq * 128 + qq * 32;
  char* Pw = smem + 32768 + w * 4096;    // wave-private P [32][64] bf16

  const int fkS = (fq == 15) ? 2 : 0;
  const int niter = (fq + 1) - (fq == 15 ? 1 : 0);   // tiles per half (ntiles always even)

  // Q fragments direct from global (B-operand: lane holds Q[q0+mf*16+lr][kk*32+lg*8..+8])
  bf16x8 aq[2][2];
#pragma unroll
  for (int kk = 0; kk < 2; ++kk)
#pragma unroll
    for (int mf = 0; mf < 2; ++mf)
      aq[kk][mf] = *(const bf16x8*)(qb + hoff + (size_t)(q0 + mf * 16 + lr) * 64 + kk * 32 + lg * 8);

  // stage tile 0 of both halves (pre-swizzled source, linear LDS dest; 4 glds16/thread)
  {
    int c = t, row = c >> 3, sl = c & 7, sp = sl ^ (row & 7);
    glds16(kb + hoff + (size_t)((fkS) * 64 + row) * 64 + sp * 8,         Kl + c * 16);
    glds16(kb + hoff + (size_t)((fkS + niter) * 64 + row) * 64 + sp * 8, Kl + 8192 + c * 16);
    glds16(vT + hoff + (size_t)row * 2048 + (fkS) * 64 + sp * 8,         Vl + c * 16);
    glds16(vT + hoff + (size_t)row * 2048 + (fkS + niter) * 64 + sp * 8, Vl + 8192 + c * 16);
  }
  __syncthreads();

  f32x4 acc[2][4] = {};                  // O^T accumulator [mf(q)][df(d)]
  float m_run[2] = {-INFINITY, -INFINITY};
  float l_run[2] = {0.0f, 0.0f};

  for (int it = 0; it < niter; ++it) {
    // T14: reg-prefetch next tile of both halves
    const bool pref = (it + 1 < niter);
    bf16x8 rK0, rK1, rV0, rV1;
    if (pref) {
      int c = t, row = c >> 3, sl = c & 7, sp = sl ^ (row & 7);
      rK0 = *(const bf16x8*)(kb + hoff + (size_t)((fkS + it + 1) * 64 + row) * 64 + sp * 8);
      rK1 = *(const bf16x8*)(kb + hoff + (size_t)((fkS + niter + it + 1) * 64 + row) * 64 + sp * 8);
      rV0 = *(const bf16x8*)(vT + hoff + (size_t)row * 2048 + (fkS + it + 1) * 64 + sp * 8);
      rV1 = *(const bf16x8*)(vT + hoff + (size_t)row * 2048 + (fkS + niter + it + 1) * 64 + sp * 8);
    }
    char* Kc = Kl + half * 8192;
    char* Vc = Vl + half * 8192;

    // S^T = K Q^T
    f32x4 st[2][4] = {};
    __builtin_amdgcn_s_setprio(1);
#pragma unroll
    for (int kk = 0; kk < 2; ++kk)
#pragma unroll
      for (int nf = 0; nf < 4; ++nf) {
        int rk = nf * 16 + lr;
        bf16x8 bk = *(const bf16x8*)(Kc + rk * 128 + (((kk * 4 + lg) ^ (rk & 7)) << 4));
        st[0][nf] = __builtin_amdgcn_mfma_f32_16x16x32_bf16(bk, aq[kk][0], st[0][nf], 0, 0, 0);
        st[1][nf] = __builtin_amdgcn_mfma_f32_16x16x32_bf16(bk, aq[kk][1], st[1][nf], 0, 0, 0);
      }
    __builtin_amdgcn_s_setprio(0);

    // in-register online softmax (lane owns q=lr per mf; k over (nf,r) in-lane + lg cross-lane)
#pragma unroll
    for (int mf = 0; mf < 2; ++mf) {
      float mx = st[mf][0][0];
#pragma unroll
      for (int nf = 0; nf < 4; ++nf)
#pragma unroll
        for (int r = 0; r < 4; ++r) mx = fmaxf(mx, st[mf][nf][r]);
      mx *= 0.125f;
      mx = fmaxf(mx, __shfl_xor(mx, 16));
      mx = fmaxf(mx, __shfl_xor(mx, 32));
      float mnew = m_run[mf], cr = 1.0f;
      if (__any(mx > m_run[mf] + 8.0f)) {       // T13 defer-max
        mnew = fmaxf(m_run[mf], mx);
        cr = __expf(m_run[mf] - mnew);
#pragma unroll
        for (int df = 0; df < 4; ++df) acc[mf][df] *= cr;
      }
      float lsum = 0.0f;
#pragma unroll
      for (int nf = 0; nf < 4; ++nf)
#pragma unroll
        for (int r = 0; r < 4; ++r) {
          float p = __expf(fmaf(st[mf][nf][r], 0.125f, -mnew));
          st[mf][nf][r] = p;
          lsum += p;
        }
      lsum += __shfl_xor(lsum, 16);
      lsum += __shfl_xor(lsum, 32);
      l_run[mf] = l_run[mf] * cr + lsum;
      m_run[mf] = mnew;

      // P^T -> wave-private LDS stripe as P[q][k]
#pragma unroll
      for (int nf = 0; nf < 4; ++nf) {
        int row = mf * 16 + lr;
        bf16x4 pw;
#pragma unroll
        for (int r = 0; r < 4; ++r) pw[r] = (__bf16)st[mf][nf][r];
        int slot = nf * 2 + (lg >> 1);
        *(bf16x4*)(Pw + row * 128 + (((slot ^ (lr & 7)) << 4) | ((lg & 1) * 8))) = pw;
      }
    }

    // O^T += V^T P^T
    __builtin_amdgcn_s_setprio(1);
#pragma unroll
    for (int kk = 0; kk < 2; ++kk) {
      bf16x8 ap[2];
#pragma unroll
      for (int mf = 0; mf < 2; ++mf) {
        int row = mf * 16 + lr;
        ap[mf] = *(const bf16x8*)(Pw + row * 128 + (((kk * 4 + lg) ^ (lr & 7)) << 4));
      }
#pragma unroll
      for (int df = 0; df < 4; ++df) {
        int rv = df * 16 + lr;
        bf16x8 av = *(const bf16x8*)(Vc + rv * 128 + (((kk * 4 + lg) ^ (rv & 7)) << 4));
        acc[0][df] = __builtin_amdgcn_mfma_f32_16x16x32_bf16(av, ap[0], acc[0][df], 0, 0, 0);
        acc[1][df] = __builtin_amdgcn_mfma_f32_16x16x32_bf16(av, ap[1], acc[1][df], 0, 0, 0);
      }
    }
    __builtin_amdgcn_s_setprio(0);

    __syncthreads();                     // all reads of current tiles done
    if (pref) {
      int c = t;
      *(bf16x8*)(Kl + c * 16)        = rK0;
      *(bf16x8*)(Kl + 8192 + c * 16) = rK1;
      *(bf16x8*)(Vl + c * 16)        = rV0;
      *(bf16x8*)(Vl + 8192 + c * 16) = rV1;
      __syncthreads();                   // writes visible
    }
  }

  // ---- merge the two KV-halves (K/V and P regions are dead now) ----
  __syncthreads();
  if (half == 1) {
    char* Ob = smem + qq * 8192;                         // O partial: 8KB per qq
#pragma unroll
    for (int mf = 0; mf < 2; ++mf)
#pragma unroll
      for (int df = 0; df < 4; ++df)
        *(f32x4*)(Ob + (mf * 4 + df) * 1024 + lane * 16) = acc[mf][df];
    if (lg == 0) {
#pragma unroll
      for (int mf = 0; mf < 2; ++mf)
        *(float2*)(smem + 32768 + qq * 1024 + mf * 128 + lr * 8) =
            make_float2(m_run[mf], l_run[mf]);
    }
  }
  __syncthreads();
  if (half == 0) {
    char* Ob = smem + qq * 8192;
    const int b = bh >> 4, h = bh & 15;
#pragma unroll
    for (int mf = 0; mf < 2; ++mf) {
      float2 ml1 = *(const float2*)(smem + 32768 + qq * 1024 + mf * 128 + lr * 8);
      float m = fmaxf(m_run[mf], ml1.x);
      float a0 = __expf(m_run[mf] - m);
      float a1 = __expf(ml1.x - m);
      float linv = 1.0f / (l_run[mf] * a0 + ml1.y * a1);
      int l = q0 + mf * 16 + lr;
#pragma unroll
      for (int df = 0; df < 4; ++df) {
        f32x4 o1 = *(const f32x4*)(Ob + (mf * 4 + df) * 1024 + lane * 16);
        bf16x4 ov;
#pragma unroll
        for (int r = 0; r < 4; ++r)
          ov[r] = (__bf16)((acc[mf][df][r] * a0 + o1[r] * a1) * linv);
        int d0 = df * 16 + lg * 4;
        *(bf16x4*)(ob + ((size_t)(b * 2048 + l)) * 1024 + h * 64 + d0) = ov;
      }
    }
  }
}

// ---------------- launch ----------------
extern "C" void kernel_launch(void* const* d_in, const int* in_sizes, int n_in,
                              void* d_out, int out_size, void* d_ws, size_t ws_size,
                              hipStream_t stream) {
  (void)in_sizes; (void)n_in; (void)out_size; (void)ws_size;
  const float* x    = (const float*)d_in[0];
  const float* Wqkv = (const float*)d_in[1];
  const float* bqkv = (const float*)d_in[2];
  const float* Wout = (const float*)d_in[3];
  const float* bout = (const float*)d_in[4];
  const float* qg   = (const float*)d_in[5];
  const float* kg   = (const float*)d_in[6];

  char* ws = (char*)d_ws;
  __bf16* xb   = (__bf16*)(ws);                 // 4096x1024       (8 MB)
  __bf16* wqb  = (__bf16*)(ws + 8388608);       // 3072x1024       (6 MB)
  __bf16* wob  = (__bf16*)(ws + 14680064);      // 1024x1024       (2 MB)
  __bf16* qbuf = (__bf16*)(ws + 16777216);      // [2][16][2048][64]
  __bf16* kbuf = (__bf16*)(ws + 25165824);
  __bf16* vbuf = (__bf16*)(ws + 33554432);      // V^T: [2][16][64][2048]
  __bf16* aob  = (__bf16*)(ws + 41943040);      // [2][2048][1024]
  float2* rtab = (float2*)(ws + 50331648);      // [2048][32] cos/sin

  prep_kernel<<<8448, 256, 0, stream>>>(x, xb, 1048576, Wqkv, wqb, 786432,
                                        Wout, wob, 262144, rtab);
  gemm_bt<0, 128><<<768, 512, 0, stream>>>(xb, wqb, 1024, 24, bqkv, qbuf, kbuf, vbuf, nullptr,
                                           qg, kg, rtab);
  attn_kernel<<<512, 512, 0, stream>>>(qbuf, kbuf, vbuf, aob);
  gemm_bt<1, 64><<<512, 512, 0, stream>>>(aob, wob, 1024, 8, bout, nullptr, nullptr, nullptr,
                                          (float*)d_out, nullptr, nullptr, nullptr);
}